// Round 9
// baseline (129.583 us; speedup 1.0000x reference)
//
#include <hip/hip_runtime.h>
#include <math.h>

// Problem constants
#define B_  512
#define C_  64
#define T_  512
#define H_  128
#define N_  (B_*C_)   // 32768

typedef unsigned int   uint_;
typedef unsigned short ushort_;
typedef unsigned long long ull_;

typedef __attribute__((ext_vector_type(8))) short bf8v;   // 8 bf16 (4 VGPRs)
typedef __attribute__((ext_vector_type(4))) float f4v;    // MFMA accumulator

#define BN_SCALE 4194304.0        // 2^22 fixed-point for deterministic BN sums

// Workspace byte offsets
#define OFF_SIMP   0u             // 512*4096*4 = 8,388,608 ; reused as Z2 later
#define OFF_Z2     0u
#define OFF_Z1     8388608u       // bf16 32768x128 = 8,388,608
#define OFF_Z3     16777216u      // 8,388,608
#define OFF_WT1    25165824u      // 128*512*2 = 131,072
#define OFF_WT2    25296896u      // 32,768
#define OFF_WT3    25329664u      // 32,768
#define OFF_MASKS  25362432u      // 64*8 = 512
#define OFF_BNACC  25406464u      // 3 * 256 * 8 = 6,144
#define OFF_Y1T    33554432u      // 512*128*64*2 = 8,388,608

__device__ __forceinline__ ushort_ f2bf(float f) {
    uint_ u = __float_as_uint(f);
    u = (u + 0x7FFFu + ((u >> 16) & 1u)) >> 16;    // RNE (finite values only)
    return (ushort_)u;
}
__device__ __forceinline__ float bf2f(ushort_ s) {
    return __uint_as_float(((uint_)s) << 16);
}

// global -> LDS direct DMA, 16 bytes per lane (wave-uniform base + lane*16).
__device__ __forceinline__ void gload_lds16(const void* g, void* l) {
    __builtin_amdgcn_global_load_lds(
        (const __attribute__((address_space(1))) void*)g,
        (__attribute__((address_space(3))) void*)l, 16, 0, 0);
}

// ---------------------------------------------------------------------------
// Graph-matrix helpers (unchanged semantics).
// ---------------------------------------------------------------------------
__device__ __forceinline__ void m_preamble_wave0(const ull_* __restrict__ masks,
                                                 ull_* nbrmS, float* dvS, int t)
{
    if (t < 64) {
        ull_ mask = masks[t];
        nbrmS[t] = mask;
        int deg = 1;                   // self-loop
#pragma unroll
        for (int d = 0; d < 64; ++d) {
            ull_ bal = __ballot((int)((mask >> d) & 1ull));
            if (t == d) deg += (int)__popcll(bal);
        }
        dvS[t] = 1.0f / sqrtf((float)deg);
    }
}

__device__ __forceinline__ void m_build(const ull_* nbrmS, const float* dvS,
                                        int t, uint_ m8[8])
{
    const int d = t >> 2, q = t & 3;
    const float dvd = dvS[d];
#pragma unroll
    for (int p = 0; p < 8; ++p) {
        int c0 = 16 * q + 2 * p, c1 = c0 + 1;
        float w0 = (float)((int)((nbrmS[c0] >> d) & 1ull) + (c0 == d ? 1 : 0));
        float w1 = (float)((int)((nbrmS[c1] >> d) & 1ull) + (c1 == d ? 1 : 0));
        m8[p] = (uint_)f2bf(w0 * dvS[c0] * dvd) |
                ((uint_)f2bf(w1 * dvS[c1] * dvd) << 16);
    }
}

// ---------------------------------------------------------------------------
// Weight prep (standalone, must precede k_gramg1): bf16 transposed weights.
//   blocks 0-7 : Wt1p[f][kappa], kappa = c*8+m  <- W1[64m+c][f]
//   blocks 8-9 : Wt2[f][k] <- W2[k][f] ; 10-11: Wt3.
// ---------------------------------------------------------------------------
__global__ __launch_bounds__(256) void k_prepw(const float* __restrict__ W1,
    const float* __restrict__ W2, const float* __restrict__ W3,
    ushort_* __restrict__ Wt1, ushort_* __restrict__ Wt2, ushort_* __restrict__ Wt3)
{
    __shared__ float L[64 * 132];
    const int blk = blockIdx.x, t = threadIdx.x;

    if (blk < 8) {
        for (int it = 0; it < 8; ++it) {
            int i = t + 256 * it;
            int ri = i >> 5, f4 = i & 31;
            int m = ri >> 3, cr = ri & 7;
            *(float4*)&L[ri * 132 + 4 * f4] =
                *(const float4*)&W1[(size_t)(64 * m + 8 * blk + cr) * H_ + 4 * f4];
        }
        __syncthreads();
        int f = t >> 1, half = t & 1;
        uint_ buf[16];
#pragma unroll
        for (int jj = 0; jj < 16; ++jj) {
            int k0 = 32 * half + 2 * jj;
            int c0 = k0 >> 3, m0 = k0 & 7;
            int c1 = (k0 + 1) >> 3, m1 = (k0 + 1) & 7;
            buf[jj] = (uint_)f2bf(L[(m0 * 8 + c0) * 132 + f]) |
                      ((uint_)f2bf(L[(m1 * 8 + c1) * 132 + f]) << 16);
        }
        ushort_* dst = Wt1 + (size_t)f * 512 + 64 * blk + 32 * half;
#pragma unroll
        for (int q = 0; q < 4; ++q) {
            uint4 vv = {buf[4 * q], buf[4 * q + 1], buf[4 * q + 2], buf[4 * q + 3]};
            *(uint4*)&dst[8 * q] = vv;
        }
    } else {
        const float* W = (blk < 10) ? W2 : W3;
        ushort_*     O = (blk < 10) ? Wt2 : Wt3;
        int kb = (blk - 8) & 1;
        for (int it = 0; it < 8; ++it) {
            int i = t + 256 * it;
            int ri = i >> 5, f4 = i & 31;
            *(float4*)&L[ri * 132 + 4 * f4] =
                *(const float4*)&W[(size_t)(64 * kb + ri) * H_ + 4 * f4];
        }
        __syncthreads();
        int f = t >> 1, half = t & 1;
        uint_ buf[16];
#pragma unroll
        for (int jj = 0; jj < 16; ++jj) {
            int k0 = 32 * half + 2 * jj;
            buf[jj] = (uint_)f2bf(L[k0 * 132 + f]) |
                      ((uint_)f2bf(L[(k0 + 1) * 132 + f]) << 16);
        }
        ushort_* dst = O + (size_t)f * 128 + 64 * kb + 32 * half;
#pragma unroll
        for (int q = 0; q < 4; ++q) {
            uint4 vv = {buf[4 * q], buf[4 * q + 1], buf[4 * q + 2], buf[4 * q + 3]};
            *(uint4*)&dst[8 * q] = vv;
        }
    }
}

// ---------------------------------------------------------------------------
// Kernel 1 (FUSED gram + layer-1 GEMM), 512 threads / 8 waves, 512 blocks.
// Chunk j stages all 64 channels x t-window [128j,128j+128) as hi/lo bf16.
//  - gram: wave w -> tile-pair (rp=w>>1, ct=2*(w&1)+{0,1}), identical to r8.
//  - gemm: chunk j holds A-rows r in [16j,16j+16) (nodes[r][kappa]=x[c][8r+m]);
//    wave w computes f-tile w over full K (16 k32-blocks, c = 4s+lg ascending
//    -> SAME kappa-block order as old mgemm1 -> bit-identical Y1).
// Y1^T accumulates in LDS [128f][64r] (stride 72), stored once, coalesced.
// ---------------------------------------------------------------------------
__global__ __launch_bounds__(512, 4) void k_gramg1(const float* __restrict__ x,
    float* __restrict__ simpart, const ushort_* __restrict__ Wt,
    ushort_* __restrict__ Y1t)
{
    __shared__ ushort_ Xh[64 * 136];     // 17408 B
    __shared__ ushort_ Xl[64 * 136];     // 17408 B
    __shared__ ushort_ Y1f[128 * 72];    // 18432 B  [f][r] stride 72
    __shared__ float  gd[64];
    __shared__ double rn[64];

    const int b = blockIdx.x;
    const int t = threadIdx.x;
    const int w = t >> 6, l = t & 63;
    const int lr = l & 15, lg = l >> 4;
    const int rp = w >> 1, ch = w & 1;

    f4v gacc[2];
#pragma unroll
    for (int i = 0; i < 2; ++i) gacc[i] = (f4v)0.f;

    const float* xb = x + (size_t)b * (C_ * T_);

    for (int j = 0; j < 4; ++j) {
        // ---- stage chunk (identical to round 8, Xhg store removed) ----
#pragma unroll
        for (int it = 0; it < 4; ++it) {
            int i = t + 512 * it;              // 2048 float4s
            int c = i >> 5, t4 = i & 31;
            float4 v = *(const float4*)&xb[(size_t)c * T_ + 128 * j + 4 * t4];
            ushort_ h0 = f2bf(v.x), h1 = f2bf(v.y), h2 = f2bf(v.z), h3 = f2bf(v.w);
            uint2 ph;
            ph.x = (uint_)h0 | ((uint_)h1 << 16);
            ph.y = (uint_)h2 | ((uint_)h3 << 16);
            float e0 = v.x - bf2f(h0), e1 = v.y - bf2f(h1);
            float e2 = v.z - bf2f(h2), e3 = v.w - bf2f(h3);
            uint2 pl;
            pl.x = (uint_)f2bf(e0) | ((uint_)f2bf(e1) << 16);
            pl.y = (uint_)f2bf(e2) | ((uint_)f2bf(e3) << 16);
            *(uint2*)&Xh[c * 136 + 4 * t4] = ph;
            *(uint2*)&Xl[c * 136 + 4 * t4] = pl;
        }
        __syncthreads();

        // ---- gram MFMA (identical to round 8) ----
#pragma unroll
        for (int s = 0; s < 4; ++s) {
            bf8v ah = *(const bf8v*)&Xh[(16 * rp + lr) * 136 + 32 * s + 8 * lg];
            bf8v al = *(const bf8v*)&Xl[(16 * rp + lr) * 136 + 32 * s + 8 * lg];
#pragma unroll
            for (int i = 0; i < 2; ++i) {
                const int ct = 2 * ch + i;
                bf8v bh = *(const bf8v*)&Xh[(16 * ct + lr) * 136 + 32 * s + 8 * lg];
                bf8v bl = *(const bf8v*)&Xl[(16 * ct + lr) * 136 + 32 * s + 8 * lg];
                gacc[i] = __builtin_amdgcn_mfma_f32_16x16x32_bf16(ah, bh, gacc[i], 0, 0, 0);
                gacc[i] = __builtin_amdgcn_mfma_f32_16x16x32_bf16(ah, bl, gacc[i], 0, 0, 0);
                gacc[i] = __builtin_amdgcn_mfma_f32_16x16x32_bf16(al, bh, gacc[i], 0, 0, 0);
            }
        }

        // ---- layer-1 GEMM: rows [16j,16j+16), f-tile w, full K ----
        {
            f4v ga = (f4v)0.f;
#pragma unroll 4
            for (int s = 0; s < 16; ++s) {
                bf8v af = *(const bf8v*)&Xh[(4 * s + lg) * 136 + 8 * lr];
                bf8v bfv = *(const bf8v*)&Wt[(size_t)(16 * w + lr) * 512 + 32 * s + 8 * lg];
                ga = __builtin_amdgcn_mfma_f32_16x16x32_bf16(af, bfv, ga, 0, 0, 0);
            }
#pragma unroll
            for (int reg = 0; reg < 4; ++reg)
                Y1f[(16 * w + lr) * 72 + 16 * j + 4 * lg + reg] = f2bf(ga[reg]);
        }
        __syncthreads();
    }

    // ---- gram diagonal / norms / simp (identical to round 8) ----
    {
        const int di = rp - 2 * ch;
        if ((di == 0 || di == 1) && lg == (lr >> 2))
            gd[16 * rp + lr] = gacc[di][lr & 3];
    }
    __syncthreads();
    if (t < 64) rn[t] = 1.0 / fmax(sqrt((double)gd[t]), 1e-12);
    __syncthreads();

    float* sp = simpart + (size_t)b * 4096;
#pragma unroll
    for (int i = 0; i < 2; ++i)
#pragma unroll
        for (int reg = 0; reg < 4; ++reg) {
            int rc = 16 * rp + 4 * lg + reg;
            int cc = 16 * (2 * ch + i) + lr;
            sp[rc * 64 + cc] = (float)((double)gacc[i][reg] * rn[rc] * rn[cc]);
        }

    // ---- Y1^T store: [b][f][r], coalesced ----
#pragma unroll
    for (int it = 0; it < 2; ++it) {
        int i = t + 512 * it;                 // 1024 uint4
        int f = i >> 3, seg = i & 7;
        *(uint4*)&Y1t[(size_t)b * 8192 + f * 64 + 8 * seg] =
            *(const uint4*)&Y1f[f * 72 + 8 * seg];
    }
}

// ---------------------------------------------------------------------------
// Kernel 2: fused batch-reduction + rank-select top-K (unchanged).
// ---------------------------------------------------------------------------
__global__ __launch_bounds__(1024) void k_simrank(const float* __restrict__ simpart,
                                                  ull_* __restrict__ masks)
{
    __shared__ double part[16][64];
    __shared__ double sd[64];
    const int c = blockIdx.x;
    const int t = threadIdx.x;
    const int d = t & 63, g = t >> 6;

    double a = 0.0;
    const float* sp = simpart + (size_t)c * 64 + d;
    for (int i = 0; i < 32; ++i)
        a += (double)sp[(size_t)(g + 16 * i) * 4096];
    part[g][d] = a;
    __syncthreads();

    if (t < 64) {
        double s = 0.0;
#pragma unroll
        for (int q = 0; q < 16; ++q) s += part[q][t];
        sd[t] = s;
        int rank = 0;
#pragma unroll
        for (int dp = 0; dp < 64; ++dp) {
            double w = sd[dp];
            rank += (w > s || (w == s && dp < t)) ? 1 : 0;
        }
        ull_ m = __ballot(rank < 16);
        if (t == 0) masks[c] = m;
    }
}

// ---------------------------------------------------------------------------
// Shared MFMA epilogue: Z = M@Y + bias, fixed-point atomic BN, Z store.
// ---------------------------------------------------------------------------
__device__ __forceinline__ void mfma_epilogue(char* smem, int b, int t,
    f4v acc[8], const float* __restrict__ bias, const uint_ m8[8],
    ushort_* __restrict__ Zout, ull_* __restrict__ bnacc)
{
    const int l = t & 63, w = t >> 6;
    const int lr = l & 15, lg = l >> 4;

    ushort_* Yt  = (ushort_*)smem;             // [128][88]
    ushort_* Ml  = (ushort_*)(smem + 22528);   // [64][88]
    ushort_* Zst = (ushort_*)(smem + 33792);   // [64][136]

#pragma unroll
    for (int nt = 0; nt < 8; ++nt) {
        uint2 p;
        p.x = (uint_)f2bf(acc[nt][0]) | ((uint_)f2bf(acc[nt][1]) << 16);
        p.y = (uint_)f2bf(acc[nt][2]) | ((uint_)f2bf(acc[nt][3]) << 16);
        *(uint2*)&Yt[(16 * nt + lr) * 88 + 16 * w + 4 * lg] = p;
    }
    {
        const int d = t >> 2, q = t & 3;
        uint4 v0 = {m8[0], m8[1], m8[2], m8[3]};
        uint4 v1 = {m8[4], m8[5], m8[6], m8[7]};
        *(uint4*)&Ml[d * 88 + 16 * q]     = v0;
        *(uint4*)&Ml[d * 88 + 16 * q + 8] = v1;
    }
    __syncthreads();

    f4v z[8];
#pragma unroll
    for (int nt = 0; nt < 8; ++nt) z[nt] = (f4v)0.f;
#pragma unroll
    for (int cs = 0; cs < 2; ++cs) {
        bf8v mf = *(const bf8v*)&Ml[(16 * w + lr) * 88 + 32 * cs + 8 * lg];
#pragma unroll
        for (int nt = 0; nt < 8; ++nt) {
            bf8v yf = *(const bf8v*)&Yt[(16 * nt + lr) * 88 + 32 * cs + 8 * lg];
            z[nt] = __builtin_amdgcn_mfma_f32_16x16x32_bf16(mf, yf, z[nt], 0, 0, 0);
        }
    }

#pragma unroll
    for (int nt = 0; nt < 8; ++nt) {
        float bv = bias[16 * nt + lr];
#pragma unroll
        for (int reg = 0; reg < 4; ++reg)
            Zst[(16 * w + 4 * lg + reg) * 136 + 16 * nt + lr] = f2bf(z[nt][reg] + bv);
    }
    __syncthreads();

    if (t < 128) {
        float s = 0.f, s2 = 0.f;
        for (int r = 0; r < 64; ++r) {
            float v = bf2f(Zst[r * 136 + t]);
            s += v; s2 += v * v;
        }
        atomicAdd(&bnacc[t],       (ull_)(long long)__double2ll_rn((double)s  * BN_SCALE));
        atomicAdd(&bnacc[128 + t], (ull_)(long long)__double2ll_rn((double)s2 * BN_SCALE));
    }
#pragma unroll
    for (int it = 0; it < 4; ++it) {
        int i = t + 256 * it;
        int r = i >> 4, seg = i & 15;
        *(uint4*)&Zout[((size_t)(b * 64 + r)) * 128 + 8 * seg] =
            *(const uint4*)&Zst[r * 136 + 8 * seg];
    }
}

// ---------------------------------------------------------------------------
// Kernel 3: mix layer 1 -> Z1 = M @ Y1 + b1 (identical math to old epilogue).
// ---------------------------------------------------------------------------
__global__ __launch_bounds__(256) void k_mix1(const ushort_* __restrict__ Y1t,
    const float* __restrict__ bias, const ull_* __restrict__ masks,
    ushort_* __restrict__ Zout, ull_* __restrict__ bnacc)
{
    __shared__ __align__(16) char smem[51200];
    __shared__ ull_  nbrmS[64];
    __shared__ float dvS[64];
    ushort_* Yt  = (ushort_*)smem;             // [128][88]
    ushort_* Ml  = (ushort_*)(smem + 22528);   // [64][88]
    ushort_* Zst = (ushort_*)(smem + 33792);   // [64][136]

    const int b = blockIdx.x;
    const int t = threadIdx.x;
    const int l = t & 63, w = t >> 6;
    const int lr = l & 15, lg = l >> 4;

    m_preamble_wave0(masks, nbrmS, dvS, t);

    // stage Y^T from global into Yt[f][r] (stride 88)
#pragma unroll
    for (int it = 0; it < 8; ++it) {
        int i = t + 256 * it;                 // 2048 uint4
        int f = i >> 3, seg = i & 7;
        *(uint4*)&Yt[f * 88 + 8 * seg] =
            *(const uint4*)&Y1t[(size_t)b * 8192 + f * 64 + 8 * seg];
    }
    __syncthreads();

    uint_ m8[8];
    m_build(nbrmS, dvS, t, m8);
    {
        const int d = t >> 2, q = t & 3;
        uint4 v0 = {m8[0], m8[1], m8[2], m8[3]};
        uint4 v1 = {m8[4], m8[5], m8[6], m8[7]};
        *(uint4*)&Ml[d * 88 + 16 * q]     = v0;
        *(uint4*)&Ml[d * 88 + 16 * q + 8] = v1;
    }
    __syncthreads();

    f4v z[8];
#pragma unroll
    for (int nt = 0; nt < 8; ++nt) z[nt] = (f4v)0.f;
#pragma unroll
    for (int cs = 0; cs < 2; ++cs) {
        bf8v mf = *(const bf8v*)&Ml[(16 * w + lr) * 88 + 32 * cs + 8 * lg];
#pragma unroll
        for (int nt = 0; nt < 8; ++nt) {
            bf8v yf = *(const bf8v*)&Yt[(16 * nt + lr) * 88 + 32 * cs + 8 * lg];
            z[nt] = __builtin_amdgcn_mfma_f32_16x16x32_bf16(mf, yf, z[nt], 0, 0, 0);
        }
    }

#pragma unroll
    for (int nt = 0; nt < 8; ++nt) {
        float bv = bias[16 * nt + lr];
#pragma unroll
        for (int reg = 0; reg < 4; ++reg)
            Zst[(16 * w + 4 * lg + reg) * 136 + 16 * nt + lr] = f2bf(z[nt][reg] + bv);
    }
    __syncthreads();

    if (t < 128) {
        float s = 0.f, s2 = 0.f;
        for (int r = 0; r < 64; ++r) {
            float v = bf2f(Zst[r * 136 + t]);
            s += v; s2 += v * v;
        }
        atomicAdd(&bnacc[t],       (ull_)(long long)__double2ll_rn((double)s  * BN_SCALE));
        atomicAdd(&bnacc[128 + t], (ull_)(long long)__double2ll_rn((double)s2 * BN_SCALE));
    }
#pragma unroll
    for (int it = 0; it < 4; ++it) {
        int i = t + 256 * it;
        int r = i >> 4, seg = i & 15;
        *(uint4*)&Zout[((size_t)(b * 64 + r)) * 128 + 8 * seg] =
            *(const uint4*)&Zst[r * 136 + 8 * seg];
    }
}

// ---------------------------------------------------------------------------
// Layers 2/3: inline BN-finalize (from bnaccIn) + inline-M + GEMM.
// ---------------------------------------------------------------------------
__global__ __launch_bounds__(256) void k_mgemm23(const ushort_* __restrict__ Zin,
    const ull_* __restrict__ bnaccIn, const float* __restrict__ g,
    const float* __restrict__ be, const ushort_* __restrict__ Wt,
    const float* __restrict__ bias, const ull_* __restrict__ masks,
    ushort_* __restrict__ Zout, ull_* __restrict__ bnaccOut)
{
    __shared__ __align__(16) char smem[51200];
    __shared__ float ssL[256];
    __shared__ ull_  nbrmS[64];
    __shared__ float dvS[64];
    ushort_* Al = (ushort_*)smem;              // [64][136]
    ushort_* Wl = (ushort_*)(smem + 17408);    // [128][128]

    const int b = blockIdx.x;
    const int t = threadIdx.x;
    const int l = t & 63, w = t >> 6;
    const int lr = l & 15, lg = l >> 4;

    // --- BN finalize preamble (reads 256 fixed-point sums) ---
    {
        long long ll = (long long)bnaccIn[t];
        double sv = (double)ll * (1.0 / BN_SCALE);
        double* sumsL = (double*)smem;
        sumsL[t] = sv;
        m_preamble_wave0(masks, nbrmS, dvS, t);
        __syncthreads();
        if (t < 128) {
            double s = sumsL[t], s2 = sumsL[128 + t];
            double mean = s * (1.0 / 32768.0);
            double var  = s2 * (1.0 / 32768.0) - mean * mean;
            double rstd = 1.0 / sqrt(var + 1e-5);
            float sc = (float)((double)g[t] * rstd);
            ssL[t]       = sc;
            ssL[128 + t] = (float)((double)be[t] - mean * (double)sc);
        }
        __syncthreads();
    }

    // W: linear 32 KB DMA
    {
        const char* wsrc = (const char*)Wt + t * 16;
        char* wdst = smem + 17408 + t * 16;
#pragma unroll
        for (int i2 = 0; i2 < 8; ++i2)
            gload_lds16(wsrc + i2 * 4096, wdst + i2 * 4096);
    }

    f4v acc[8];
#pragma unroll
    for (int nt = 0; nt < 8; ++nt) acc[nt] = (f4v)0.f;

    // stage A with BN fold + relu
#pragma unroll
    for (int it = 0; it < 4; ++it) {
        int i = t + 256 * it;
        int r = i >> 4, seg = i & 15;
        uint4 v = *(const uint4*)&Zin[((size_t)(b * 64 + r)) * 128 + 8 * seg];
        uint_ w0[4] = {v.x, v.y, v.z, v.w};
        uint_ o[4];
#pragma unroll
        for (int p = 0; p < 4; ++p) {
            int f0 = 8 * seg + 2 * p;
            float z0 = bf2f((ushort_)(w0[p] & 0xFFFF));
            float z1 = bf2f((ushort_)(w0[p] >> 16));
            float h0 = fmaxf(fmaf(z0, ssL[f0],     ssL[128 + f0]),     0.f);
            float h1 = fmaxf(fmaf(z1, ssL[f0 + 1], ssL[128 + f0 + 1]), 0.f);
            o[p] = (uint_)f2bf(h0) | ((uint_)f2bf(h1) << 16);
        }
        uint4 ov = {o[0], o[1], o[2], o[3]};
        *(uint4*)&Al[r * 136 + 8 * seg] = ov;
    }
    __syncthreads();
#pragma unroll
    for (int s = 0; s < 4; ++s) {
        bf8v af = *(const bf8v*)&Al[(16 * w + lr) * 136 + 32 * s + 8 * lg];
#pragma unroll
        for (int nt = 0; nt < 8; ++nt) {
            bf8v bfv = *(const bf8v*)&Wl[(16 * nt + lr) * 128 + 32 * s + 8 * lg];
            acc[nt] = __builtin_amdgcn_mfma_f32_16x16x32_bf16(af, bfv, acc[nt], 0, 0, 0);
        }
    }
    __syncthreads();

    uint_ m8[8];
    m_build(nbrmS, dvS, t, m8);
    mfma_epilogue(smem, b, t, acc, bias, m8, Zout, bnaccOut);
}

// ---------------------------------------------------------------------------
// Final BN + ReLU with inline BN-finalize (from fixed-point sums).
// ---------------------------------------------------------------------------
__global__ __launch_bounds__(256) void k_out(const ushort_* __restrict__ Z,
    const ull_* __restrict__ bnaccIn, const float* __restrict__ g,
    const float* __restrict__ be, float* __restrict__ out)
{
    __shared__ double sumsL[256];
    __shared__ float  ssL[256];
    const int b = blockIdx.x;
    const int t = threadIdx.x;

    sumsL[t] = (double)(long long)bnaccIn[t] * (1.0 / BN_SCALE);
    __syncthreads();
    if (t < 128) {
        double s = sumsL[t], s2 = sumsL[128 + t];
        double mean = s * (1.0 / 32768.0);
        double var  = s2 * (1.0 / 32768.0) - mean * mean;
        double rstd = 1.0 / sqrt(var + 1e-5);
        float sc = (float)((double)g[t] * rstd);
        ssL[t]       = sc;
        ssL[128 + t] = (float)((double)be[t] - mean * (double)sc);
    }
    __syncthreads();

    const size_t base = (size_t)b * 64 * 128;
#pragma unroll
    for (int it = 0; it < 8; ++it) {
        int i = t + 256 * it;
        int r = i >> 5, s = i & 31;
        uint2 v = *(const uint2*)&Z[base + (size_t)r * 128 + 4 * s];
        float4 sc = *(const float4*)&ssL[4 * s];
        float4 sh = *(const float4*)&ssL[128 + 4 * s];
        float z0 = bf2f((ushort_)(v.x & 0xFFFF));
        float z1 = bf2f((ushort_)(v.x >> 16));
        float z2 = bf2f((ushort_)(v.y & 0xFFFF));
        float z3 = bf2f((ushort_)(v.y >> 16));
        float4 o;
        o.x = fmaxf(fmaf(z0, sc.x, sh.x), 0.f);
        o.y = fmaxf(fmaf(z1, sc.y, sh.y), 0.f);
        o.z = fmaxf(fmaf(z2, sc.z, sh.z), 0.f);
        o.w = fmaxf(fmaf(z3, sc.w, sh.w), 0.f);
        *(float4*)&out[base + (size_t)r * 128 + 4 * s] = o;
    }
}

// ---------------------------------------------------------------------------
extern "C" void kernel_launch(void* const* d_in, const int* in_sizes, int n_in,
                              void* d_out, int out_size, void* d_ws, size_t ws_size,
                              hipStream_t stream)
{
    (void)in_sizes; (void)n_in; (void)out_size; (void)ws_size;

    const float* x   = (const float*)d_in[0];
    const float* W1  = (const float*)d_in[9];
    const float* b1  = (const float*)d_in[10];
    const float* g1  = (const float*)d_in[11];
    const float* be1 = (const float*)d_in[12];
    const float* W2  = (const float*)d_in[13];
    const float* b2  = (const float*)d_in[14];
    const float* g2  = (const float*)d_in[15];
    const float* be2 = (const float*)d_in[16];
    const float* W3  = (const float*)d_in[17];
    const float* b3  = (const float*)d_in[18];
    const float* g3  = (const float*)d_in[19];
    const float* be3 = (const float*)d_in[20];

    char* ws = (char*)d_ws;
    float*   simp   = (float*)(ws + OFF_SIMP);
    ull_*    masks  = (ull_*)(ws + OFF_MASKS);
    ushort_* Wt1    = (ushort_*)(ws + OFF_WT1);
    ushort_* Wt2    = (ushort_*)(ws + OFF_WT2);
    ushort_* Wt3    = (ushort_*)(ws + OFF_WT3);
    ull_*    bnacc1 = (ull_*)(ws + OFF_BNACC);
    ull_*    bnacc2 = bnacc1 + 256;
    ull_*    bnacc3 = bnacc1 + 512;
    ushort_* Y1t    = (ushort_*)(ws + OFF_Y1T);
    ushort_* Z1     = (ushort_*)(ws + OFF_Z1);
    ushort_* Z2     = (ushort_*)(ws + OFF_Z2);   // reuses simp region
    ushort_* Z3     = (ushort_*)(ws + OFF_Z3);
    float*   out    = (float*)d_out;

    hipMemsetAsync(ws + OFF_BNACC, 0, 3 * 256 * sizeof(ull_), stream);

    k_prepw<<<dim3(12), dim3(256), 0, stream>>>(W1, W2, W3, Wt1, Wt2, Wt3);
    k_gramg1<<<dim3(512), dim3(512), 0, stream>>>(x, simp, Wt1, Y1t);
    k_simrank<<<dim3(64), dim3(1024), 0, stream>>>(simp, masks);

    k_mix1<<<dim3(512), dim3(256), 0, stream>>>(Y1t, b1, masks, Z1, bnacc1);
    k_mgemm23<<<dim3(512), dim3(256), 0, stream>>>(Z1, bnacc1, g1, be1, Wt2, b2, masks, Z2, bnacc2);
    k_mgemm23<<<dim3(512), dim3(256), 0, stream>>>(Z2, bnacc2, g2, be2, Wt3, b3, masks, Z3, bnacc3);
    k_out<<<dim3(512), dim3(256), 0, stream>>>(Z3, bnacc3, g3, be3, out);
}

// Round 10
// 119.634 us; speedup vs baseline: 1.0832x; 1.0832x over previous
//
#include <hip/hip_runtime.h>
#include <math.h>

// Problem constants
#define B_  512
#define C_  64
#define T_  512
#define H_  128
#define N_  (B_*C_)   // 32768

typedef unsigned int   uint_;
typedef unsigned short ushort_;
typedef unsigned long long ull_;

typedef __attribute__((ext_vector_type(8))) short bf8v;   // 8 bf16 (4 VGPRs)
typedef __attribute__((ext_vector_type(4))) float f4v;    // MFMA accumulator

#define BN_SCALE 4194304.0        // 2^22 fixed-point for deterministic BN sums

// Workspace byte offsets
#define OFF_SIMP   0u            // 512*4096*4 = 8,388,608 ; reused as Z2 later
#define OFF_Z2     0u
#define OFF_Z1     8388608u      // 8,388,608 (bf16 32768x128)
#define OFF_Z3     16777216u     // 8,388,608
#define OFF_WT1    25165824u     // 128*512*2 = 131,072
#define OFF_WT2    25296896u     // 32,768
#define OFF_WT3    25329664u     // 32,768
#define OFF_MASKS  25362432u     // 64*8 = 512
#define OFF_BNACC  25406464u     // 3 * 256 * 8 = 6,144
#define OFF_XH     33554432u     // 512*64*512*2 = 33,554,432 -> end 67,108,864

__device__ __forceinline__ ushort_ f2bf(float f) {
    uint_ u = __float_as_uint(f);
    u = (u + 0x7FFFu + ((u >> 16) & 1u)) >> 16;    // RNE (finite values only)
    return (ushort_)u;
}
__device__ __forceinline__ float bf2f(ushort_ s) {
    return __uint_as_float(((uint_)s) << 16);
}

// global -> LDS direct DMA, 16 bytes per lane (wave-uniform base + lane*16).
__device__ __forceinline__ void gload_lds16(const void* g, void* l) {
    __builtin_amdgcn_global_load_lds(
        (const __attribute__((address_space(1))) void*)g,
        (__attribute__((address_space(3))) void*)l, 16, 0, 0);
}

// ---------------------------------------------------------------------------
// Graph-matrix helpers.
// ---------------------------------------------------------------------------
__device__ __forceinline__ void m_preamble_wave0(const ull_* __restrict__ masks,
                                                 ull_* nbrmS, float* dvS, int t)
{
    if (t < 64) {
        ull_ mask = masks[t];
        nbrmS[t] = mask;
        int deg = 1;                   // self-loop
#pragma unroll
        for (int d = 0; d < 64; ++d) {
            ull_ bal = __ballot((int)((mask >> d) & 1ull));
            if (t == d) deg += (int)__popcll(bal);
        }
        dvS[t] = 1.0f / sqrtf((float)deg);
    }
}

__device__ __forceinline__ void m_build(const ull_* nbrmS, const float* dvS,
                                        int t, uint_ m8[8])
{
    const int d = t >> 2, q = t & 3;
    const float dvd = dvS[d];
#pragma unroll
    for (int p = 0; p < 8; ++p) {
        int c0 = 16 * q + 2 * p, c1 = c0 + 1;
        float w0 = (float)((int)((nbrmS[c0] >> d) & 1ull) + (c0 == d ? 1 : 0));
        float w1 = (float)((int)((nbrmS[c1] >> d) & 1ull) + (c1 == d ? 1 : 0));
        m8[p] = (uint_)f2bf(w0 * dvS[c0] * dvd) |
                ((uint_)f2bf(w1 * dvS[c1] * dvd) << 16);
    }
}

// ---------------------------------------------------------------------------
// Kernel 1 (512 threads / 8 waves): blocks <512 = per-batch split-precision
// bf16 MFMA gram (+ persist Xh); blocks 512..523 = weight prep.
// (round-8 verified version, unchanged)
// ---------------------------------------------------------------------------
__global__ __launch_bounds__(512, 4) void k_gramw(const float* __restrict__ x,
    float* __restrict__ simpart, ushort_* __restrict__ Xhg,
    const float* __restrict__ W1, const float* __restrict__ W2,
    const float* __restrict__ W3,
    ushort_* __restrict__ Wt1, ushort_* __restrict__ Wt2, ushort_* __restrict__ Wt3)
{
    __shared__ __align__(16) char smem[35584];
    __shared__ float  gd[64];
    __shared__ double rn[64];
    const int blk = blockIdx.x;
    const int t = threadIdx.x;

    if (blk < 512) {
        ushort_* Xh = (ushort_*)smem;              // [64][136]
        ushort_* Xl = (ushort_*)(smem + 17408);    // [64][136]
        const int b = blk;
        const int w = t >> 6, l = t & 63;
        const int lr = l & 15, lg = l >> 4;
        const int rp = w >> 1, ch = w & 1;         // row-tile, col-half

        f4v acc[2];
#pragma unroll
        for (int i = 0; i < 2; ++i) acc[i] = (f4v)0.f;

        const float* xb = x + (size_t)b * (C_ * T_);

        for (int j = 0; j < 4; ++j) {
#pragma unroll
            for (int it = 0; it < 4; ++it) {
                int i = t + 512 * it;              // 2048 float4s
                int c = i >> 5, t4 = i & 31;
                float4 v = *(const float4*)&xb[(size_t)c * T_ + 128 * j + 4 * t4];
                ushort_ h0 = f2bf(v.x), h1 = f2bf(v.y), h2 = f2bf(v.z), h3 = f2bf(v.w);
                uint2 ph;
                ph.x = (uint_)h0 | ((uint_)h1 << 16);
                ph.y = (uint_)h2 | ((uint_)h3 << 16);
                float e0 = v.x - bf2f(h0), e1 = v.y - bf2f(h1);
                float e2 = v.z - bf2f(h2), e3 = v.w - bf2f(h3);
                uint2 pl;
                pl.x = (uint_)f2bf(e0) | ((uint_)f2bf(e1) << 16);
                pl.y = (uint_)f2bf(e2) | ((uint_)f2bf(e3) << 16);
                *(uint2*)&Xh[c * 136 + 4 * t4] = ph;
                *(uint2*)&Xl[c * 136 + 4 * t4] = pl;
                // persist hi bits for layer-1 GEMM (bit-identical reuse)
                *(uint2*)&Xhg[(((size_t)(b * 64 + c)) << 9) + 128 * j + 4 * t4] = ph;
            }
            __syncthreads();

#pragma unroll
            for (int s = 0; s < 4; ++s) {
                bf8v ah = *(const bf8v*)&Xh[(16 * rp + lr) * 136 + 32 * s + 8 * lg];
                bf8v al = *(const bf8v*)&Xl[(16 * rp + lr) * 136 + 32 * s + 8 * lg];
#pragma unroll
                for (int i = 0; i < 2; ++i) {
                    const int ct = 2 * ch + i;
                    bf8v bh = *(const bf8v*)&Xh[(16 * ct + lr) * 136 + 32 * s + 8 * lg];
                    bf8v bl = *(const bf8v*)&Xl[(16 * ct + lr) * 136 + 32 * s + 8 * lg];
                    acc[i] = __builtin_amdgcn_mfma_f32_16x16x32_bf16(ah, bh, acc[i], 0, 0, 0);
                    acc[i] = __builtin_amdgcn_mfma_f32_16x16x32_bf16(ah, bl, acc[i], 0, 0, 0);
                    acc[i] = __builtin_amdgcn_mfma_f32_16x16x32_bf16(al, bh, acc[i], 0, 0, 0);
                }
            }
            __syncthreads();
        }

        // diagonal extraction: wave holds diag tile iff rp - 2*ch in {0,1}
        {
            const int di = rp - 2 * ch;
            if ((di == 0 || di == 1) && lg == (lr >> 2))
                gd[16 * rp + lr] = acc[di][lr & 3];
        }
        __syncthreads();
        if (t < 64) rn[t] = 1.0 / fmax(sqrt((double)gd[t]), 1e-12);
        __syncthreads();

        float* sp = simpart + (size_t)b * 4096;
#pragma unroll
        for (int i = 0; i < 2; ++i)
#pragma unroll
            for (int reg = 0; reg < 4; ++reg) {
                int rc = 16 * rp + 4 * lg + reg;
                int cc = 16 * (2 * ch + i) + lr;
                sp[rc * 64 + cc] = (float)((double)acc[i][reg] * rn[rc] * rn[cc]);
            }
    } else {
        // ---- weight prep (512-thread variant), pblk in 0..11 ----
        float* L = (float*)smem;                   // [64][132]
        const int pblk = blk - 512;
        if (pblk < 8) {
#pragma unroll
            for (int it = 0; it < 4; ++it) {
                int i = t + 512 * it;
                int ri = i >> 5, f4 = i & 31;
                int m = ri >> 3, cr = ri & 7;
                *(float4*)&L[ri * 132 + 4 * f4] =
                    *(const float4*)&W1[(size_t)(64 * m + 8 * pblk + cr) * H_ + 4 * f4];
            }
            __syncthreads();
            int f = t >> 2, q = t & 3;
            uint_ buf[8];
#pragma unroll
            for (int jj = 0; jj < 8; ++jj) {
                int k0 = 16 * q + 2 * jj;
                int c0 = k0 >> 3, m0 = k0 & 7;
                int c1 = (k0 + 1) >> 3, m1 = (k0 + 1) & 7;
                buf[jj] = (uint_)f2bf(L[(m0 * 8 + c0) * 132 + f]) |
                          ((uint_)f2bf(L[(m1 * 8 + c1) * 132 + f]) << 16);
            }
            ushort_* dst = Wt1 + (size_t)f * 512 + 64 * pblk + 16 * q;
            uint4 v0 = {buf[0], buf[1], buf[2], buf[3]};
            uint4 v1 = {buf[4], buf[5], buf[6], buf[7]};
            *(uint4*)&dst[0] = v0;
            *(uint4*)&dst[8] = v1;
        } else {
            const float* W = (pblk < 10) ? W2 : W3;
            ushort_*     O = (pblk < 10) ? Wt2 : Wt3;
            int kb = (pblk - 8) & 1;
#pragma unroll
            for (int it = 0; it < 4; ++it) {
                int i = t + 512 * it;
                int ri = i >> 5, f4 = i & 31;
                *(float4*)&L[ri * 132 + 4 * f4] =
                    *(const float4*)&W[(size_t)(64 * kb + ri) * H_ + 4 * f4];
            }
            __syncthreads();
            int f = t >> 2, q = t & 3;
            uint_ buf[8];
#pragma unroll
            for (int jj = 0; jj < 8; ++jj) {
                int k0 = 16 * q + 2 * jj;
                buf[jj] = (uint_)f2bf(L[k0 * 132 + f]) |
                          ((uint_)f2bf(L[(k0 + 1) * 132 + f]) << 16);
            }
            ushort_* dst = O + (size_t)f * 128 + 64 * kb + 16 * q;
            uint4 v0 = {buf[0], buf[1], buf[2], buf[3]};
            uint4 v1 = {buf[4], buf[5], buf[6], buf[7]};
            *(uint4*)&dst[0] = v0;
            *(uint4*)&dst[8] = v1;
        }
    }
}

// ---------------------------------------------------------------------------
// Kernel 2: fused batch-reduction + rank-select top-K (1024 threads).
// ---------------------------------------------------------------------------
__global__ __launch_bounds__(1024) void k_simrank(const float* __restrict__ simpart,
                                                  ull_* __restrict__ masks)
{
    __shared__ double part[16][64];
    __shared__ double sd[64];
    const int c = blockIdx.x;
    const int t = threadIdx.x;
    const int d = t & 63, g = t >> 6;

    double a = 0.0;
    const float* sp = simpart + (size_t)c * 64 + d;
    for (int i = 0; i < 32; ++i)
        a += (double)sp[(size_t)(g + 16 * i) * 4096];
    part[g][d] = a;
    __syncthreads();

    if (t < 64) {
        double s = 0.0;
#pragma unroll
        for (int q = 0; q < 16; ++q) s += part[q][t];
        sd[t] = s;
        int rank = 0;
#pragma unroll
        for (int dp = 0; dp < 64; ++dp) {
            double w = sd[dp];
            rank += (w > s || (w == s && dp < t)) ? 1 : 0;
        }
        ull_ m = __ballot(rank < 16);
        if (t == 0) masks[c] = m;
    }
}

// ---------------------------------------------------------------------------
// Shared MFMA epilogue: Z = M@Y + bias, fixed-point atomic BN, Z store.
// Integer atomics are associative -> deterministic across replays.
// ---------------------------------------------------------------------------
__device__ __forceinline__ void mfma_epilogue(char* smem, int b, int t,
    f4v acc[8], const float* __restrict__ bias, const uint_ m8[8],
    ushort_* __restrict__ Zout, ull_* __restrict__ bnacc)
{
    const int l = t & 63, w = t >> 6;
    const int lr = l & 15, lg = l >> 4;

    ushort_* Yt  = (ushort_*)smem;             // [128][88]
    ushort_* Ml  = (ushort_*)(smem + 22528);   // [64][88]
    ushort_* Zst = (ushort_*)(smem + 33792);   // [64][136]

#pragma unroll
    for (int nt = 0; nt < 8; ++nt) {
        uint2 p;
        p.x = (uint_)f2bf(acc[nt][0]) | ((uint_)f2bf(acc[nt][1]) << 16);
        p.y = (uint_)f2bf(acc[nt][2]) | ((uint_)f2bf(acc[nt][3]) << 16);
        *(uint2*)&Yt[(16 * nt + lr) * 88 + 16 * w + 4 * lg] = p;
    }
    {
        const int d = t >> 2, q = t & 3;
        uint4 v0 = {m8[0], m8[1], m8[2], m8[3]};
        uint4 v1 = {m8[4], m8[5], m8[6], m8[7]};
        *(uint4*)&Ml[d * 88 + 16 * q]     = v0;
        *(uint4*)&Ml[d * 88 + 16 * q + 8] = v1;
    }
    __syncthreads();

    f4v z[8];
#pragma unroll
    for (int nt = 0; nt < 8; ++nt) z[nt] = (f4v)0.f;
#pragma unroll
    for (int cs = 0; cs < 2; ++cs) {
        bf8v mf = *(const bf8v*)&Ml[(16 * w + lr) * 88 + 32 * cs + 8 * lg];
#pragma unroll
        for (int nt = 0; nt < 8; ++nt) {
            bf8v yf = *(const bf8v*)&Yt[(16 * nt + lr) * 88 + 32 * cs + 8 * lg];
            z[nt] = __builtin_amdgcn_mfma_f32_16x16x32_bf16(mf, yf, z[nt], 0, 0, 0);
        }
    }

#pragma unroll
    for (int nt = 0; nt < 8; ++nt) {
        float bv = bias[16 * nt + lr];
#pragma unroll
        for (int reg = 0; reg < 4; ++reg)
            Zst[(16 * w + 4 * lg + reg) * 136 + 16 * nt + lr] = f2bf(z[nt][reg] + bv);
    }
    __syncthreads();

    if (t < 128) {
        float s = 0.f, s2 = 0.f;
        for (int r = 0; r < 64; ++r) {
            float v = bf2f(Zst[r * 136 + t]);
            s += v; s2 += v * v;
        }
        atomicAdd(&bnacc[t],       (ull_)(long long)__double2ll_rn((double)s  * BN_SCALE));
        atomicAdd(&bnacc[128 + t], (ull_)(long long)__double2ll_rn((double)s2 * BN_SCALE));
    }
#pragma unroll
    for (int it = 0; it < 4; ++it) {
        int i = t + 256 * it;
        int r = i >> 4, seg = i & 15;
        *(uint4*)&Zout[((size_t)(b * 64 + r)) * 128 + 8 * seg] =
            *(const uint4*)&Zst[r * 136 + 8 * seg];
    }
}

// ---------------------------------------------------------------------------
// Layer 1: A and W staged via global_load_lds DMA; A = persisted Xh.
// ---------------------------------------------------------------------------
__global__ __launch_bounds__(256) void k_mgemm1(const ushort_* __restrict__ Xh,
    const ushort_* __restrict__ Wt, const float* __restrict__ bias,
    const ull_* __restrict__ masks, ushort_* __restrict__ Zout,
    ull_* __restrict__ bnacc)
{
    __shared__ __align__(16) char smem[51456];
    __shared__ ull_  nbrmS[64];
    __shared__ float dvS[64];
    ushort_* Al = (ushort_*)smem;              // [16][512] per chunk
    ushort_* Wl = (ushort_*)(smem + 16384);    // [128][128] per chunk

    const int b = blockIdx.x;
    const int t = threadIdx.x;
    const int l = t & 63, w = t >> 6;
    const int lr = l & 15, lg = l >> 4;

    m_preamble_wave0(masks, nbrmS, dvS, t);

    f4v acc[8];
#pragma unroll
    for (int nt = 0; nt < 8; ++nt) acc[nt] = (f4v)0.f;

    for (int j = 0; j < 4; ++j) {
        {
            const char* asrc = (const char*)(Xh + (((size_t)(b * 64 + 16 * j)) << 9)) + t * 16;
            char* adst = smem + t * 16;
#pragma unroll
            for (int i2 = 0; i2 < 4; ++i2)
                gload_lds16(asrc + i2 * 4096, adst + i2 * 4096);
        }
        {
            const int fr = t >> 4, seg = t & 15;
            const char* wsrc = (const char*)(Wt + (size_t)fr * 512 + 128 * j + seg * 8);
            char* wdst = smem + 16384 + t * 16;
#pragma unroll
            for (int i2 = 0; i2 < 8; ++i2)
                gload_lds16(wsrc + i2 * 16384, wdst + i2 * 4096);
        }
        __syncthreads();
#pragma unroll
        for (int s = 0; s < 4; ++s) {
            bf8v af = *(const bf8v*)&Al[(4 * s + lg) * 512 + 128 * w + 8 * lr];
#pragma unroll
            for (int nt = 0; nt < 8; ++nt) {
                bf8v bfv = *(const bf8v*)&Wl[(16 * nt + lr) * 128 + 32 * s + 8 * lg];
                acc[nt] = __builtin_amdgcn_mfma_f32_16x16x32_bf16(af, bfv, acc[nt], 0, 0, 0);
            }
        }
        __syncthreads();
    }

    uint_ m8[8];
    m_build(nbrmS, dvS, t, m8);
    mfma_epilogue(smem, b, t, acc, bias, m8, Zout, bnacc);
}

// ---------------------------------------------------------------------------
// Layers 2/3: inline BN-finalize (fixed-point sums) + inline-M + GEMM.
// ---------------------------------------------------------------------------
__global__ __launch_bounds__(256) void k_mgemm23(const ushort_* __restrict__ Zin,
    const ull_* __restrict__ bnaccIn, const float* __restrict__ g,
    const float* __restrict__ be, const ushort_* __restrict__ Wt,
    const float* __restrict__ bias, const ull_* __restrict__ masks,
    ushort_* __restrict__ Zout, ull_* __restrict__ bnaccOut)
{
    __shared__ __align__(16) char smem[52224];
    __shared__ float ssL[256];
    __shared__ ull_  nbrmS[64];
    __shared__ float dvS[64];
    ushort_* Al = (ushort_*)smem;              // [64][136]
    ushort_* Wl = (ushort_*)(smem + 17408);    // [128][128]

    const int b = blockIdx.x;
    const int t = threadIdx.x;
    const int l = t & 63, w = t >> 6;
    const int lr = l & 15, lg = l >> 4;

    // --- BN finalize preamble: 256 fixed-point sums -> scale/shift ---
    {
        double* sumsL = (double*)smem;
        sumsL[t] = (double)(long long)bnaccIn[t] * (1.0 / BN_SCALE);
        m_preamble_wave0(masks, nbrmS, dvS, t);
        __syncthreads();
        if (t < 128) {
            double s = sumsL[t], s2 = sumsL[128 + t];
            double mean = s * (1.0 / 32768.0);
            double var  = s2 * (1.0 / 32768.0) - mean * mean;
            double rstd = 1.0 / sqrt(var + 1e-5);
            float sc = (float)((double)g[t] * rstd);
            ssL[t]       = sc;
            ssL[128 + t] = (float)((double)be[t] - mean * (double)sc);
        }
        __syncthreads();
    }

    // W: linear 32 KB DMA (overlaps the A-staging VALU below)
    {
        const char* wsrc = (const char*)Wt + t * 16;
        char* wdst = smem + 17408 + t * 16;
#pragma unroll
        for (int i2 = 0; i2 < 8; ++i2)
            gload_lds16(wsrc + i2 * 4096, wdst + i2 * 4096);
    }

    f4v acc[8];
#pragma unroll
    for (int nt = 0; nt < 8; ++nt) acc[nt] = (f4v)0.f;

    // stage A with BN fold + relu
#pragma unroll
    for (int it = 0; it < 4; ++it) {
        int i = t + 256 * it;
        int r = i >> 4, seg = i & 15;
        uint4 v = *(const uint4*)&Zin[((size_t)(b * 64 + r)) * 128 + 8 * seg];
        uint_ w0[4] = {v.x, v.y, v.z, v.w};
        uint_ o[4];
#pragma unroll
        for (int p = 0; p < 4; ++p) {
            int f0 = 8 * seg + 2 * p;
            float z0 = bf2f((ushort_)(w0[p] & 0xFFFF));
            float z1 = bf2f((ushort_)(w0[p] >> 16));
            float h0 = fmaxf(fmaf(z0, ssL[f0],     ssL[128 + f0]),     0.f);
            float h1 = fmaxf(fmaf(z1, ssL[f0 + 1], ssL[128 + f0 + 1]), 0.f);
            o[p] = (uint_)f2bf(h0) | ((uint_)f2bf(h1) << 16);
        }
        uint4 ov = {o[0], o[1], o[2], o[3]};
        *(uint4*)&Al[r * 136 + 8 * seg] = ov;
    }
    __syncthreads();
#pragma unroll
    for (int s = 0; s < 4; ++s) {
        bf8v af = *(const bf8v*)&Al[(16 * w + lr) * 136 + 32 * s + 8 * lg];
#pragma unroll
        for (int nt = 0; nt < 8; ++nt) {
            bf8v bfv = *(const bf8v*)&Wl[(16 * nt + lr) * 128 + 32 * s + 8 * lg];
            acc[nt] = __builtin_amdgcn_mfma_f32_16x16x32_bf16(af, bfv, acc[nt], 0, 0, 0);
        }
    }
    __syncthreads();

    uint_ m8[8];
    m_build(nbrmS, dvS, t, m8);
    mfma_epilogue(smem, b, t, acc, bias, m8, Zout, bnaccOut);
}

// ---------------------------------------------------------------------------
// Final BN + ReLU with inline BN-finalize (from fixed-point sums).
// ---------------------------------------------------------------------------
__global__ __launch_bounds__(256) void k_out(const ushort_* __restrict__ Z,
    const ull_* __restrict__ bnaccIn, const float* __restrict__ g,
    const float* __restrict__ be, float* __restrict__ out)
{
    __shared__ double sumsL[256];
    __shared__ float  ssL[256];
    const int b = blockIdx.x;
    const int t = threadIdx.x;

    sumsL[t] = (double)(long long)bnaccIn[t] * (1.0 / BN_SCALE);
    __syncthreads();
    if (t < 128) {
        double s = sumsL[t], s2 = sumsL[128 + t];
        double mean = s * (1.0 / 32768.0);
        double var  = s2 * (1.0 / 32768.0) - mean * mean;
        double rstd = 1.0 / sqrt(var + 1e-5);
        float sc = (float)((double)g[t] * rstd);
        ssL[t]       = sc;
        ssL[128 + t] = (float)((double)be[t] - mean * (double)sc);
    }
    __syncthreads();

    const size_t base = (size_t)b * 64 * 128;
#pragma unroll
    for (int it = 0; it < 8; ++it) {
        int i = t + 256 * it;
        int r = i >> 5, s = i & 31;
        uint2 v = *(const uint2*)&Z[base + (size_t)r * 128 + 4 * s];
        float4 sc = *(const float4*)&ssL[4 * s];
        float4 sh = *(const float4*)&ssL[128 + 4 * s];
        float z0 = bf2f((ushort_)(v.x & 0xFFFF));
        float z1 = bf2f((ushort_)(v.x >> 16));
        float z2 = bf2f((ushort_)(v.y & 0xFFFF));
        float z3 = bf2f((ushort_)(v.y >> 16));
        float4 o;
        o.x = fmaxf(fmaf(z0, sc.x, sh.x), 0.f);
        o.y = fmaxf(fmaf(z1, sc.y, sh.y), 0.f);
        o.z = fmaxf(fmaf(z2, sc.z, sh.z), 0.f);
        o.w = fmaxf(fmaf(z3, sc.w, sh.w), 0.f);
        *(float4*)&out[base + (size_t)r * 128 + 4 * s] = o;
    }
}

// ---------------------------------------------------------------------------
extern "C" void kernel_launch(void* const* d_in, const int* in_sizes, int n_in,
                              void* d_out, int out_size, void* d_ws, size_t ws_size,
                              hipStream_t stream)
{
    (void)in_sizes; (void)n_in; (void)out_size; (void)ws_size;

    const float* x   = (const float*)d_in[0];
    const float* W1  = (const float*)d_in[9];
    const float* b1  = (const float*)d_in[10];
    const float* g1  = (const float*)d_in[11];
    const float* be1 = (const float*)d_in[12];
    const float* W2  = (const float*)d_in[13];
    const float* b2  = (const float*)d_in[14];
    const float* g2  = (const float*)d_in[15];
    const float* be2 = (const float*)d_in[16];
    const float* W3  = (const float*)d_in[17];
    const float* b3  = (const float*)d_in[18];
    const float* g3  = (const float*)d_in[19];
    const float* be3 = (const float*)d_in[20];

    char* ws = (char*)d_ws;
    float*   simp   = (float*)(ws + OFF_SIMP);
    ull_*    masks  = (ull_*)(ws + OFF_MASKS);
    ushort_* Wt1    = (ushort_*)(ws + OFF_WT1);
    ushort_* Wt2    = (ushort_*)(ws + OFF_WT2);
    ushort_* Wt3    = (ushort_*)(ws + OFF_WT3);
    ull_*    bnacc1 = (ull_*)(ws + OFF_BNACC);
    ull_*    bnacc2 = bnacc1 + 256;
    ull_*    bnacc3 = bnacc1 + 512;
    ushort_* Xh     = (ushort_*)(ws + OFF_XH);
    ushort_* Z1     = (ushort_*)(ws + OFF_Z1);
    ushort_* Z2     = (ushort_*)(ws + OFF_Z2);   // reuses simp region
    ushort_* Z3     = (ushort_*)(ws + OFF_Z3);
    float*   out    = (float*)d_out;

    hipMemsetAsync(ws + OFF_BNACC, 0, 3 * 256 * sizeof(ull_), stream);

    k_gramw<<<dim3(524), dim3(512), 0, stream>>>(x, simp, Xh, W1, W2, W3, Wt1, Wt2, Wt3);
    k_simrank<<<dim3(64), dim3(1024), 0, stream>>>(simp, masks);

    k_mgemm1<<<dim3(512), dim3(256), 0, stream>>>(Xh, Wt1, b1, masks, Z1, bnacc1);
    k_mgemm23<<<dim3(512), dim3(256), 0, stream>>>(Z1, bnacc1, g1, be1, Wt2, b2, masks, Z2, bnacc2);
    k_mgemm23<<<dim3(512), dim3(256), 0, stream>>>(Z2, bnacc2, g2, be2, Wt3, b3, masks, Z3, bnacc3);
    k_out<<<dim3(512), dim3(256), 0, stream>>>(Z3, bnacc3, g3, be3, out);
}

// Round 11
// 114.496 us; speedup vs baseline: 1.1318x; 1.0449x over previous
//
#include <hip/hip_runtime.h>
#include <math.h>

// Problem constants
#define B_  512
#define C_  64
#define T_  512
#define H_  128
#define N_  (B_*C_)   // 32768

typedef unsigned int   uint_;
typedef unsigned short ushort_;
typedef unsigned long long ull_;

typedef __attribute__((ext_vector_type(8))) short bf8v;   // 8 bf16 (4 VGPRs)
typedef __attribute__((ext_vector_type(4))) float f4v;    // MFMA accumulator

#define BN_SCALE 4194304.0        // 2^22 fixed-point for deterministic BN sums

// Workspace byte offsets
#define OFF_SIMP   0u            // 512*4096*4 = 8,388,608 ; reused as Z2 later
#define OFF_Z2     0u
#define OFF_Z1     8388608u      // 8,388,608 (bf16 32768x128)
#define OFF_Z3     16777216u     // 8,388,608
#define OFF_WT1    25165824u     // 128*512*2 = 131,072
#define OFF_WT2    25296896u     // 32,768
#define OFF_WT3    25329664u     // 32,768
#define OFF_MASKS  25362432u     // 64*8 = 512
#define OFF_BNACC  25406464u     // 3 * 256 * 8 = 6,144
#define OFF_XH     33554432u     // 512*64*512*2 = 33,554,432 -> end 67,108,864

__device__ __forceinline__ ushort_ f2bf(float f) {
    uint_ u = __float_as_uint(f);
    u = (u + 0x7FFFu + ((u >> 16) & 1u)) >> 16;    // RNE (finite values only)
    return (ushort_)u;
}
__device__ __forceinline__ float bf2f(ushort_ s) {
    return __uint_as_float(((uint_)s) << 16);
}

// global -> LDS direct DMA, 16 bytes per lane (wave-uniform base + lane*16).
__device__ __forceinline__ void gload_lds16(const void* g, void* l) {
    __builtin_amdgcn_global_load_lds(
        (const __attribute__((address_space(1))) void*)g,
        (__attribute__((address_space(3))) void*)l, 16, 0, 0);
}

// ---------------------------------------------------------------------------
// Graph-matrix helpers.
// ---------------------------------------------------------------------------
__device__ __forceinline__ void m_preamble_wave0(const ull_* __restrict__ masks,
                                                 ull_* nbrmS, float* dvS, int t)
{
    if (t < 64) {
        ull_ mask = masks[t];
        nbrmS[t] = mask;
        int deg = 1;                   // self-loop
#pragma unroll
        for (int d = 0; d < 64; ++d) {
            ull_ bal = __ballot((int)((mask >> d) & 1ull));
            if (t == d) deg += (int)__popcll(bal);
        }
        dvS[t] = 1.0f / sqrtf((float)deg);
    }
}

__device__ __forceinline__ void m_build(const ull_* nbrmS, const float* dvS,
                                        int t, uint_ m8[8])
{
    const int d = t >> 2, q = t & 3;
    const float dvd = dvS[d];
#pragma unroll
    for (int p = 0; p < 8; ++p) {
        int c0 = 16 * q + 2 * p, c1 = c0 + 1;
        float w0 = (float)((int)((nbrmS[c0] >> d) & 1ull) + (c0 == d ? 1 : 0));
        float w1 = (float)((int)((nbrmS[c1] >> d) & 1ull) + (c1 == d ? 1 : 0));
        m8[p] = (uint_)f2bf(w0 * dvS[c0] * dvd) |
                ((uint_)f2bf(w1 * dvS[c1] * dvd) << 16);
    }
}

// ---------------------------------------------------------------------------
// Kernel 1 (512 threads / 8 waves): blocks <512 = per-batch split-precision
// bf16 MFMA gram (+ persist Xh); blocks 512..523 = weight prep.
// pblk==0 additionally zeroes the 768 fixed-point BN accumulators (replaces
// the hipMemsetAsync that cost ~39 us/replay as a slow runtime blit).
// ---------------------------------------------------------------------------
__global__ __launch_bounds__(512, 4) void k_gramw(const float* __restrict__ x,
    float* __restrict__ simpart, ushort_* __restrict__ Xhg,
    const float* __restrict__ W1, const float* __restrict__ W2,
    const float* __restrict__ W3,
    ushort_* __restrict__ Wt1, ushort_* __restrict__ Wt2, ushort_* __restrict__ Wt3,
    ull_* __restrict__ bnaccAll)
{
    __shared__ __align__(16) char smem[35584];
    __shared__ float  gd[64];
    __shared__ double rn[64];
    const int blk = blockIdx.x;
    const int t = threadIdx.x;

    if (blk < 512) {
        ushort_* Xh = (ushort_*)smem;              // [64][136]
        ushort_* Xl = (ushort_*)(smem + 17408);    // [64][136]
        const int b = blk;
        const int w = t >> 6, l = t & 63;
        const int lr = l & 15, lg = l >> 4;
        const int rp = w >> 1, ch = w & 1;         // row-tile, col-half

        f4v acc[2];
#pragma unroll
        for (int i = 0; i < 2; ++i) acc[i] = (f4v)0.f;

        const float* xb = x + (size_t)b * (C_ * T_);

        for (int j = 0; j < 4; ++j) {
#pragma unroll
            for (int it = 0; it < 4; ++it) {
                int i = t + 512 * it;              // 2048 float4s
                int c = i >> 5, t4 = i & 31;
                float4 v = *(const float4*)&xb[(size_t)c * T_ + 128 * j + 4 * t4];
                ushort_ h0 = f2bf(v.x), h1 = f2bf(v.y), h2 = f2bf(v.z), h3 = f2bf(v.w);
                uint2 ph;
                ph.x = (uint_)h0 | ((uint_)h1 << 16);
                ph.y = (uint_)h2 | ((uint_)h3 << 16);
                float e0 = v.x - bf2f(h0), e1 = v.y - bf2f(h1);
                float e2 = v.z - bf2f(h2), e3 = v.w - bf2f(h3);
                uint2 pl;
                pl.x = (uint_)f2bf(e0) | ((uint_)f2bf(e1) << 16);
                pl.y = (uint_)f2bf(e2) | ((uint_)f2bf(e3) << 16);
                *(uint2*)&Xh[c * 136 + 4 * t4] = ph;
                *(uint2*)&Xl[c * 136 + 4 * t4] = pl;
                // persist hi bits for layer-1 GEMM (bit-identical reuse)
                *(uint2*)&Xhg[(((size_t)(b * 64 + c)) << 9) + 128 * j + 4 * t4] = ph;
            }
            __syncthreads();

#pragma unroll
            for (int s = 0; s < 4; ++s) {
                bf8v ah = *(const bf8v*)&Xh[(16 * rp + lr) * 136 + 32 * s + 8 * lg];
                bf8v al = *(const bf8v*)&Xl[(16 * rp + lr) * 136 + 32 * s + 8 * lg];
#pragma unroll
                for (int i = 0; i < 2; ++i) {
                    const int ct = 2 * ch + i;
                    bf8v bh = *(const bf8v*)&Xh[(16 * ct + lr) * 136 + 32 * s + 8 * lg];
                    bf8v bl = *(const bf8v*)&Xl[(16 * ct + lr) * 136 + 32 * s + 8 * lg];
                    acc[i] = __builtin_amdgcn_mfma_f32_16x16x32_bf16(ah, bh, acc[i], 0, 0, 0);
                    acc[i] = __builtin_amdgcn_mfma_f32_16x16x32_bf16(ah, bl, acc[i], 0, 0, 0);
                    acc[i] = __builtin_amdgcn_mfma_f32_16x16x32_bf16(al, bh, acc[i], 0, 0, 0);
                }
            }
            __syncthreads();
        }

        // diagonal extraction: wave holds diag tile iff rp - 2*ch in {0,1}
        {
            const int di = rp - 2 * ch;
            if ((di == 0 || di == 1) && lg == (lr >> 2))
                gd[16 * rp + lr] = acc[di][lr & 3];
        }
        __syncthreads();
        if (t < 64) rn[t] = 1.0 / fmax(sqrt((double)gd[t]), 1e-12);
        __syncthreads();

        float* sp = simpart + (size_t)b * 4096;
#pragma unroll
        for (int i = 0; i < 2; ++i)
#pragma unroll
            for (int reg = 0; reg < 4; ++reg) {
                int rc = 16 * rp + 4 * lg + reg;
                int cc = 16 * (2 * ch + i) + lr;
                sp[rc * 64 + cc] = (float)((double)acc[i][reg] * rn[rc] * rn[cc]);
            }
    } else {
        // ---- weight prep (512-thread variant), pblk in 0..11 ----
        float* L = (float*)smem;                   // [64][132]
        const int pblk = blk - 512;
        if (pblk == 0) {                           // zero BN accumulators
            for (int i = t; i < 768; i += 512) bnaccAll[i] = 0ull;
        }
        if (pblk < 8) {
#pragma unroll
            for (int it = 0; it < 4; ++it) {
                int i = t + 512 * it;
                int ri = i >> 5, f4 = i & 31;
                int m = ri >> 3, cr = ri & 7;
                *(float4*)&L[ri * 132 + 4 * f4] =
                    *(const float4*)&W1[(size_t)(64 * m + 8 * pblk + cr) * H_ + 4 * f4];
            }
            __syncthreads();
            int f = t >> 2, q = t & 3;
            uint_ buf[8];
#pragma unroll
            for (int jj = 0; jj < 8; ++jj) {
                int k0 = 16 * q + 2 * jj;
                int c0 = k0 >> 3, m0 = k0 & 7;
                int c1 = (k0 + 1) >> 3, m1 = (k0 + 1) & 7;
                buf[jj] = (uint_)f2bf(L[(m0 * 8 + c0) * 132 + f]) |
                          ((uint_)f2bf(L[(m1 * 8 + c1) * 132 + f]) << 16);
            }
            ushort_* dst = Wt1 + (size_t)f * 512 + 64 * pblk + 16 * q;
            uint4 v0 = {buf[0], buf[1], buf[2], buf[3]};
            uint4 v1 = {buf[4], buf[5], buf[6], buf[7]};
            *(uint4*)&dst[0] = v0;
            *(uint4*)&dst[8] = v1;
        } else {
            const float* W = (pblk < 10) ? W2 : W3;
            ushort_*     O = (pblk < 10) ? Wt2 : Wt3;
            int kb = (pblk - 8) & 1;
#pragma unroll
            for (int it = 0; it < 4; ++it) {
                int i = t + 512 * it;
                int ri = i >> 5, f4 = i & 31;
                *(float4*)&L[ri * 132 + 4 * f4] =
                    *(const float4*)&W[(size_t)(64 * kb + ri) * H_ + 4 * f4];
            }
            __syncthreads();
            int f = t >> 2, q = t & 3;
            uint_ buf[8];
#pragma unroll
            for (int jj = 0; jj < 8; ++jj) {
                int k0 = 16 * q + 2 * jj;
                buf[jj] = (uint_)f2bf(L[k0 * 132 + f]) |
                          ((uint_)f2bf(L[(k0 + 1) * 132 + f]) << 16);
            }
            ushort_* dst = O + (size_t)f * 128 + 64 * kb + 16 * q;
            uint4 v0 = {buf[0], buf[1], buf[2], buf[3]};
            uint4 v1 = {buf[4], buf[5], buf[6], buf[7]};
            *(uint4*)&dst[0] = v0;
            *(uint4*)&dst[8] = v1;
        }
    }
}

// ---------------------------------------------------------------------------
// Kernel 2: fused batch-reduction + rank-select top-K (1024 threads).
// ---------------------------------------------------------------------------
__global__ __launch_bounds__(1024) void k_simrank(const float* __restrict__ simpart,
                                                  ull_* __restrict__ masks)
{
    __shared__ double part[16][64];
    __shared__ double sd[64];
    const int c = blockIdx.x;
    const int t = threadIdx.x;
    const int d = t & 63, g = t >> 6;

    double a = 0.0;
    const float* sp = simpart + (size_t)c * 64 + d;
    for (int i = 0; i < 32; ++i)
        a += (double)sp[(size_t)(g + 16 * i) * 4096];
    part[g][d] = a;
    __syncthreads();

    if (t < 64) {
        double s = 0.0;
#pragma unroll
        for (int q = 0; q < 16; ++q) s += part[q][t];
        sd[t] = s;
        int rank = 0;
#pragma unroll
        for (int dp = 0; dp < 64; ++dp) {
            double w = sd[dp];
            rank += (w > s || (w == s && dp < t)) ? 1 : 0;
        }
        ull_ m = __ballot(rank < 16);
        if (t == 0) masks[c] = m;
    }
}

// ---------------------------------------------------------------------------
// Shared MFMA epilogue: Z = M@Y + bias, fixed-point atomic BN, Z store.
// Integer atomics are associative -> deterministic across replays.
// ---------------------------------------------------------------------------
__device__ __forceinline__ void mfma_epilogue(char* smem, int b, int t,
    f4v acc[8], const float* __restrict__ bias, const uint_ m8[8],
    ushort_* __restrict__ Zout, ull_* __restrict__ bnacc)
{
    const int l = t & 63, w = t >> 6;
    const int lr = l & 15, lg = l >> 4;

    ushort_* Yt  = (ushort_*)smem;             // [128][88]
    ushort_* Ml  = (ushort_*)(smem + 22528);   // [64][88]
    ushort_* Zst = (ushort_*)(smem + 33792);   // [64][136]

#pragma unroll
    for (int nt = 0; nt < 8; ++nt) {
        uint2 p;
        p.x = (uint_)f2bf(acc[nt][0]) | ((uint_)f2bf(acc[nt][1]) << 16);
        p.y = (uint_)f2bf(acc[nt][2]) | ((uint_)f2bf(acc[nt][3]) << 16);
        *(uint2*)&Yt[(16 * nt + lr) * 88 + 16 * w + 4 * lg] = p;
    }
    {
        const int d = t >> 2, q = t & 3;
        uint4 v0 = {m8[0], m8[1], m8[2], m8[3]};
        uint4 v1 = {m8[4], m8[5], m8[6], m8[7]};
        *(uint4*)&Ml[d * 88 + 16 * q]     = v0;
        *(uint4*)&Ml[d * 88 + 16 * q + 8] = v1;
    }
    __syncthreads();

    f4v z[8];
#pragma unroll
    for (int nt = 0; nt < 8; ++nt) z[nt] = (f4v)0.f;
#pragma unroll
    for (int cs = 0; cs < 2; ++cs) {
        bf8v mf = *(const bf8v*)&Ml[(16 * w + lr) * 88 + 32 * cs + 8 * lg];
#pragma unroll
        for (int nt = 0; nt < 8; ++nt) {
            bf8v yf = *(const bf8v*)&Yt[(16 * nt + lr) * 88 + 32 * cs + 8 * lg];
            z[nt] = __builtin_amdgcn_mfma_f32_16x16x32_bf16(mf, yf, z[nt], 0, 0, 0);
        }
    }

#pragma unroll
    for (int nt = 0; nt < 8; ++nt) {
        float bv = bias[16 * nt + lr];
#pragma unroll
        for (int reg = 0; reg < 4; ++reg)
            Zst[(16 * w + 4 * lg + reg) * 136 + 16 * nt + lr] = f2bf(z[nt][reg] + bv);
    }
    __syncthreads();

    if (t < 128) {
        float s = 0.f, s2 = 0.f;
        for (int r = 0; r < 64; ++r) {
            float v = bf2f(Zst[r * 136 + t]);
            s += v; s2 += v * v;
        }
        atomicAdd(&bnacc[t],       (ull_)(long long)__double2ll_rn((double)s  * BN_SCALE));
        atomicAdd(&bnacc[128 + t], (ull_)(long long)__double2ll_rn((double)s2 * BN_SCALE));
    }
#pragma unroll
    for (int it = 0; it < 4; ++it) {
        int i = t + 256 * it;
        int r = i >> 4, seg = i & 15;
        *(uint4*)&Zout[((size_t)(b * 64 + r)) * 128 + 8 * seg] =
            *(const uint4*)&Zst[r * 136 + 8 * seg];
    }
}

// ---------------------------------------------------------------------------
// Layer 1: A and W staged via global_load_lds DMA; A = persisted Xh.
// ---------------------------------------------------------------------------
__global__ __launch_bounds__(256) void k_mgemm1(const ushort_* __restrict__ Xh,
    const ushort_* __restrict__ Wt, const float* __restrict__ bias,
    const ull_* __restrict__ masks, ushort_* __restrict__ Zout,
    ull_* __restrict__ bnacc)
{
    __shared__ __align__(16) char smem[51456];
    __shared__ ull_  nbrmS[64];
    __shared__ float dvS[64];
    ushort_* Al = (ushort_*)smem;              // [16][512] per chunk
    ushort_* Wl = (ushort_*)(smem + 16384);    // [128][128] per chunk

    const int b = blockIdx.x;
    const int t = threadIdx.x;
    const int l = t & 63, w = t >> 6;
    const int lr = l & 15, lg = l >> 4;

    m_preamble_wave0(masks, nbrmS, dvS, t);

    f4v acc[8];
#pragma unroll
    for (int nt = 0; nt < 8; ++nt) acc[nt] = (f4v)0.f;

    for (int j = 0; j < 4; ++j) {
        {
            const char* asrc = (const char*)(Xh + (((size_t)(b * 64 + 16 * j)) << 9)) + t * 16;
            char* adst = smem + t * 16;
#pragma unroll
            for (int i2 = 0; i2 < 4; ++i2)
                gload_lds16(asrc + i2 * 4096, adst + i2 * 4096);
        }
        {
            const int fr = t >> 4, seg = t & 15;
            const char* wsrc = (const char*)(Wt + (size_t)fr * 512 + 128 * j + seg * 8);
            char* wdst = smem + 16384 + t * 16;
#pragma unroll
            for (int i2 = 0; i2 < 8; ++i2)
                gload_lds16(wsrc + i2 * 16384, wdst + i2 * 4096);
        }
        __syncthreads();
#pragma unroll
        for (int s = 0; s < 4; ++s) {
            bf8v af = *(const bf8v*)&Al[(4 * s + lg) * 512 + 128 * w + 8 * lr];
#pragma unroll
            for (int nt = 0; nt < 8; ++nt) {
                bf8v bfv = *(const bf8v*)&Wl[(16 * nt + lr) * 128 + 32 * s + 8 * lg];
                acc[nt] = __builtin_amdgcn_mfma_f32_16x16x32_bf16(af, bfv, acc[nt], 0, 0, 0);
            }
        }
        __syncthreads();
    }

    uint_ m8[8];
    m_build(nbrmS, dvS, t, m8);
    mfma_epilogue(smem, b, t, acc, bias, m8, Zout, bnacc);
}

// ---------------------------------------------------------------------------
// Layers 2/3: inline BN-finalize (fixed-point sums) + inline-M + GEMM.
// ---------------------------------------------------------------------------
__global__ __launch_bounds__(256) void k_mgemm23(const ushort_* __restrict__ Zin,
    const ull_* __restrict__ bnaccIn, const float* __restrict__ g,
    const float* __restrict__ be, const ushort_* __restrict__ Wt,
    const float* __restrict__ bias, const ull_* __restrict__ masks,
    ushort_* __restrict__ Zout, ull_* __restrict__ bnaccOut)
{
    __shared__ __align__(16) char smem[52224];
    __shared__ float ssL[256];
    __shared__ ull_  nbrmS[64];
    __shared__ float dvS[64];
    ushort_* Al = (ushort_*)smem;              // [64][136]
    ushort_* Wl = (ushort_*)(smem + 17408);    // [128][128]

    const int b = blockIdx.x;
    const int t = threadIdx.x;
    const int l = t & 63, w = t >> 6;
    const int lr = l & 15, lg = l >> 4;

    // --- BN finalize preamble: 256 fixed-point sums -> scale/shift ---
    {
        double* sumsL = (double*)smem;
        sumsL[t] = (double)(long long)bnaccIn[t] * (1.0 / BN_SCALE);
        m_preamble_wave0(masks, nbrmS, dvS, t);
        __syncthreads();
        if (t < 128) {
            double s = sumsL[t], s2 = sumsL[128 + t];
            double mean = s * (1.0 / 32768.0);
            double var  = s2 * (1.0 / 32768.0) - mean * mean;
            double rstd = 1.0 / sqrt(var + 1e-5);
            float sc = (float)((double)g[t] * rstd);
            ssL[t]       = sc;
            ssL[128 + t] = (float)((double)be[t] - mean * (double)sc);
        }
        __syncthreads();
    }

    // W: linear 32 KB DMA (overlaps the A-staging VALU below)
    {
        const char* wsrc = (const char*)Wt + t * 16;
        char* wdst = smem + 17408 + t * 16;
#pragma unroll
        for (int i2 = 0; i2 < 8; ++i2)
            gload_lds16(wsrc + i2 * 4096, wdst + i2 * 4096);
    }

    f4v acc[8];
#pragma unroll
    for (int nt = 0; nt < 8; ++nt) acc[nt] = (f4v)0.f;

    // stage A with BN fold + relu
#pragma unroll
    for (int it = 0; it < 4; ++it) {
        int i = t + 256 * it;
        int r = i >> 4, seg = i & 15;
        uint4 v = *(const uint4*)&Zin[((size_t)(b * 64 + r)) * 128 + 8 * seg];
        uint_ w0[4] = {v.x, v.y, v.z, v.w};
        uint_ o[4];
#pragma unroll
        for (int p = 0; p < 4; ++p) {
            int f0 = 8 * seg + 2 * p;
            float z0 = bf2f((ushort_)(w0[p] & 0xFFFF));
            float z1 = bf2f((ushort_)(w0[p] >> 16));
            float h0 = fmaxf(fmaf(z0, ssL[f0],     ssL[128 + f0]),     0.f);
            float h1 = fmaxf(fmaf(z1, ssL[f0 + 1], ssL[128 + f0 + 1]), 0.f);
            o[p] = (uint_)f2bf(h0) | ((uint_)f2bf(h1) << 16);
        }
        uint4 ov = {o[0], o[1], o[2], o[3]};
        *(uint4*)&Al[r * 136 + 8 * seg] = ov;
    }
    __syncthreads();
#pragma unroll
    for (int s = 0; s < 4; ++s) {
        bf8v af = *(const bf8v*)&Al[(16 * w + lr) * 136 + 32 * s + 8 * lg];
#pragma unroll
        for (int nt = 0; nt < 8; ++nt) {
            bf8v bfv = *(const bf8v*)&Wl[(16 * nt + lr) * 128 + 32 * s + 8 * lg];
            acc[nt] = __builtin_amdgcn_mfma_f32_16x16x32_bf16(af, bfv, acc[nt], 0, 0, 0);
        }
    }
    __syncthreads();

    uint_ m8[8];
    m_build(nbrmS, dvS, t, m8);
    mfma_epilogue(smem, b, t, acc, bias, m8, Zout, bnaccOut);
}

// ---------------------------------------------------------------------------
// Final BN + ReLU with inline BN-finalize (from fixed-point sums).
// ---------------------------------------------------------------------------
__global__ __launch_bounds__(256) void k_out(const ushort_* __restrict__ Z,
    const ull_* __restrict__ bnaccIn, const float* __restrict__ g,
    const float* __restrict__ be, float* __restrict__ out)
{
    __shared__ double sumsL[256];
    __shared__ float  ssL[256];
    const int b = blockIdx.x;
    const int t = threadIdx.x;

    sumsL[t] = (double)(long long)bnaccIn[t] * (1.0 / BN_SCALE);
    __syncthreads();
    if (t < 128) {
        double s = sumsL[t], s2 = sumsL[128 + t];
        double mean = s * (1.0 / 32768.0);
        double var  = s2 * (1.0 / 32768.0) - mean * mean;
        double rstd = 1.0 / sqrt(var + 1e-5);
        float sc = (float)((double)g[t] * rstd);
        ssL[t]       = sc;
        ssL[128 + t] = (float)((double)be[t] - mean * (double)sc);
    }
    __syncthreads();

    const size_t base = (size_t)b * 64 * 128;
#pragma unroll
    for (int it = 0; it < 8; ++it) {
        int i = t + 256 * it;
        int r = i >> 5, s = i & 31;
        uint2 v = *(const uint2*)&Z[base + (size_t)r * 128 + 4 * s];
        float4 sc = *(const float4*)&ssL[4 * s];
        float4 sh = *(const float4*)&ssL[128 + 4 * s];
        float z0 = bf2f((ushort_)(v.x & 0xFFFF));
        float z1 = bf2f((ushort_)(v.x >> 16));
        float z2 = bf2f((ushort_)(v.y & 0xFFFF));
        float z3 = bf2f((ushort_)(v.y >> 16));
        float4 o;
        o.x = fmaxf(fmaf(z0, sc.x, sh.x), 0.f);
        o.y = fmaxf(fmaf(z1, sc.y, sh.y), 0.f);
        o.z = fmaxf(fmaf(z2, sc.z, sh.z), 0.f);
        o.w = fmaxf(fmaf(z3, sc.w, sh.w), 0.f);
        *(float4*)&out[base + (size_t)r * 128 + 4 * s] = o;
    }
}

// ---------------------------------------------------------------------------
extern "C" void kernel_launch(void* const* d_in, const int* in_sizes, int n_in,
                              void* d_out, int out_size, void* d_ws, size_t ws_size,
                              hipStream_t stream)
{
    (void)in_sizes; (void)n_in; (void)out_size; (void)ws_size;

    const float* x   = (const float*)d_in[0];
    const float* W1  = (const float*)d_in[9];
    const float* b1  = (const float*)d_in[10];
    const float* g1  = (const float*)d_in[11];
    const float* be1 = (const float*)d_in[12];
    const float* W2  = (const float*)d_in[13];
    const float* b2  = (const float*)d_in[14];
    const float* g2  = (const float*)d_in[15];
    const float* be2 = (const float*)d_in[16];
    const float* W3  = (const float*)d_in[17];
    const float* b3  = (const float*)d_in[18];
    const float* g3  = (const float*)d_in[19];
    const float* be3 = (const float*)d_in[20];

    char* ws = (char*)d_ws;
    float*   simp   = (float*)(ws + OFF_SIMP);
    ull_*    masks  = (ull_*)(ws + OFF_MASKS);
    ushort_* Wt1    = (ushort_*)(ws + OFF_WT1);
    ushort_* Wt2    = (ushort_*)(ws + OFF_WT2);
    ushort_* Wt3    = (ushort_*)(ws + OFF_WT3);
    ull_*    bnacc1 = (ull_*)(ws + OFF_BNACC);
    ull_*    bnacc2 = bnacc1 + 256;
    ull_*    bnacc3 = bnacc1 + 512;
    ushort_* Xh     = (ushort_*)(ws + OFF_XH);
    ushort_* Z1     = (ushort_*)(ws + OFF_Z1);
    ushort_* Z2     = (ushort_*)(ws + OFF_Z2);   // reuses simp region
    ushort_* Z3     = (ushort_*)(ws + OFF_Z3);
    float*   out    = (float*)d_out;

    k_gramw<<<dim3(524), dim3(512), 0, stream>>>(x, simp, Xh, W1, W2, W3,
                                                 Wt1, Wt2, Wt3, bnacc1);
    k_simrank<<<dim3(64), dim3(1024), 0, stream>>>(simp, masks);

    k_mgemm1<<<dim3(512), dim3(256), 0, stream>>>(Xh, Wt1, b1, masks, Z1, bnacc1);
    k_mgemm23<<<dim3(512), dim3(256), 0, stream>>>(Z1, bnacc1, g1, be1, Wt2, b2, masks, Z2, bnacc2);
    k_mgemm23<<<dim3(512), dim3(256), 0, stream>>>(Z2, bnacc2, g2, be2, Wt3, b3, masks, Z3, bnacc3);
    k_out<<<dim3(512), dim3(256), 0, stream>>>(Z3, bnacc3, g3, be3, out);
}

// Round 12
// 93.477 us; speedup vs baseline: 1.3863x; 1.2248x over previous
//
#include <hip/hip_runtime.h>
#include <math.h>

// Problem constants
#define B_  512
#define C_  64
#define T_  512
#define H_  128
#define N_  (B_*C_)   // 32768

typedef unsigned int   uint_;
typedef unsigned short ushort_;
typedef unsigned long long ull_;

typedef __attribute__((ext_vector_type(8))) short bf8v;   // 8 bf16 (4 VGPRs)
typedef __attribute__((ext_vector_type(4))) float f4v;    // MFMA accumulator

// Workspace byte offsets
#define OFF_SIMP   0u            // 512*4096*4 = 8,388,608 ; reused as Z2 later
#define OFF_Z2     0u
#define OFF_Z1     8388608u      // 8,388,608 (bf16 32768x128)
#define OFF_Z3     16777216u     // 8,388,608
#define OFF_WT1    25165824u     // 128*512*2 = 131,072
#define OFF_WT2    25296896u     // 32,768
#define OFF_WT3    25329664u     // 32,768
#define OFF_MASKS  25362432u     // 64*8 = 512
#define OFF_BNPART 25406464u     // 512*256*4 = 524,288 -> end 25,930,752
#define OFF_BNP2   25930752u     // 32*256*8  = 65,536  -> end 25,996,288
#define OFF_Y1T    33554432u     // 512*128*64*2 = 8,388,608

__device__ __forceinline__ ushort_ f2bf(float f) {
    uint_ u = __float_as_uint(f);
    u = (u + 0x7FFFu + ((u >> 16) & 1u)) >> 16;    // RNE (finite values only)
    return (ushort_)u;
}
__device__ __forceinline__ float bf2f(ushort_ s) {
    return __uint_as_float(((uint_)s) << 16);
}

// global -> LDS direct DMA, 16 bytes per lane (wave-uniform base + lane*16).
__device__ __forceinline__ void gload_lds16(const void* g, void* l) {
    __builtin_amdgcn_global_load_lds(
        (const __attribute__((address_space(1))) void*)g,
        (__attribute__((address_space(3))) void*)l, 16, 0, 0);
}

// ---------------------------------------------------------------------------
// Graph-matrix helpers.
// ---------------------------------------------------------------------------
__device__ __forceinline__ void m_preamble_wave0(const ull_* __restrict__ masks,
                                                 ull_* nbrmS, float* dvS, int t)
{
    if (t < 64) {
        ull_ mask = masks[t];
        nbrmS[t] = mask;
        int deg = 1;                   // self-loop
#pragma unroll
        for (int d = 0; d < 64; ++d) {
            ull_ bal = __ballot((int)((mask >> d) & 1ull));
            if (t == d) deg += (int)__popcll(bal);
        }
        dvS[t] = 1.0f / sqrtf((float)deg);
    }
}

__device__ __forceinline__ void m_build(const ull_* nbrmS, const float* dvS,
                                        int t, uint_ m8[8])
{
    const int d = t >> 2, q = t & 3;
    const float dvd = dvS[d];
#pragma unroll
    for (int p = 0; p < 8; ++p) {
        int c0 = 16 * q + 2 * p, c1 = c0 + 1;
        float w0 = (float)((int)((nbrmS[c0] >> d) & 1ull) + (c0 == d ? 1 : 0));
        float w1 = (float)((int)((nbrmS[c1] >> d) & 1ull) + (c1 == d ? 1 : 0));
        m8[p] = (uint_)f2bf(w0 * dvS[c0] * dvd) |
                ((uint_)f2bf(w1 * dvS[c1] * dvd) << 16);
    }
}

// ---------------------------------------------------------------------------
// Weight prep (standalone, must precede k_gramg1 which reads Wt1).
//   blocks 0-7 : Wt1p[f][kappa], kappa = c*8+m  <- W1[64m+c][f]
//   blocks 8-9 : Wt2[f][k] <- W2[k][f] ; 10-11: Wt3.
// ---------------------------------------------------------------------------
__global__ __launch_bounds__(256) void k_prepw(const float* __restrict__ W1,
    const float* __restrict__ W2, const float* __restrict__ W3,
    ushort_* __restrict__ Wt1, ushort_* __restrict__ Wt2, ushort_* __restrict__ Wt3)
{
    __shared__ float L[64 * 132];
    const int blk = blockIdx.x, t = threadIdx.x;

    if (blk < 8) {
        for (int it = 0; it < 8; ++it) {
            int i = t + 256 * it;
            int ri = i >> 5, f4 = i & 31;
            int m = ri >> 3, cr = ri & 7;
            *(float4*)&L[ri * 132 + 4 * f4] =
                *(const float4*)&W1[(size_t)(64 * m + 8 * blk + cr) * H_ + 4 * f4];
        }
        __syncthreads();
        int f = t >> 1, half = t & 1;
        uint_ buf[16];
#pragma unroll
        for (int jj = 0; jj < 16; ++jj) {
            int k0 = 32 * half + 2 * jj;
            int c0 = k0 >> 3, m0 = k0 & 7;
            int c1 = (k0 + 1) >> 3, m1 = (k0 + 1) & 7;
            buf[jj] = (uint_)f2bf(L[(m0 * 8 + c0) * 132 + f]) |
                      ((uint_)f2bf(L[(m1 * 8 + c1) * 132 + f]) << 16);
        }
        ushort_* dst = Wt1 + (size_t)f * 512 + 64 * blk + 32 * half;
#pragma unroll
        for (int q = 0; q < 4; ++q) {
            uint4 vv = {buf[4 * q], buf[4 * q + 1], buf[4 * q + 2], buf[4 * q + 3]};
            *(uint4*)&dst[8 * q] = vv;
        }
    } else {
        const float* W = (blk < 10) ? W2 : W3;
        ushort_*     O = (blk < 10) ? Wt2 : Wt3;
        int kb = (blk - 8) & 1;
        for (int it = 0; it < 8; ++it) {
            int i = t + 256 * it;
            int ri = i >> 5, f4 = i & 31;
            *(float4*)&L[ri * 132 + 4 * f4] =
                *(const float4*)&W[(size_t)(64 * kb + ri) * H_ + 4 * f4];
        }
        __syncthreads();
        int f = t >> 1, half = t & 1;
        uint_ buf[16];
#pragma unroll
        for (int jj = 0; jj < 16; ++jj) {
            int k0 = 32 * half + 2 * jj;
            buf[jj] = (uint_)f2bf(L[k0 * 132 + f]) |
                      ((uint_)f2bf(L[(k0 + 1) * 132 + f]) << 16);
        }
        ushort_* dst = O + (size_t)f * 128 + 64 * kb + 32 * half;
#pragma unroll
        for (int q = 0; q < 4; ++q) {
            uint4 vv = {buf[4 * q], buf[4 * q + 1], buf[4 * q + 2], buf[4 * q + 3]};
            *(uint4*)&dst[8 * q] = vv;
        }
    }
}

// ---------------------------------------------------------------------------
// Kernel 1 (FUSED gram + layer-1 GEMM, lean): 512 blocks x 512 threads.
// Gram path = round-8 verified code (bit-identical sim). GEMM additions:
//  - B-fragments are j-invariant (each wave's f-tile uses the same 16 Wt
//    fragments every chunk) -> preloaded ONCE into 64 VGPRs before the loop.
//  - Y1 fragment stored directly to global from regs (no extra LDS/barriers).
// K-order per output = kappa-ascending -> bit-identical Y1 to r8's mgemm1.
// LDS stays 35.5 KB.
// ---------------------------------------------------------------------------
__global__ __launch_bounds__(512, 4) void k_gramg1(const float* __restrict__ x,
    float* __restrict__ simpart, const ushort_* __restrict__ Wt,
    ushort_* __restrict__ Y1t)
{
    __shared__ ushort_ Xh[64 * 136];
    __shared__ ushort_ Xl[64 * 136];
    __shared__ float  gd[64];
    __shared__ double rn[64];

    const int b = blockIdx.x;
    const int t = threadIdx.x;
    const int w = t >> 6, l = t & 63;
    const int lr = l & 15, lg = l >> 4;
    const int rp = w >> 1, ch = w & 1;         // gram row-tile, col-half

    // preload the wave's 16 B-fragments (f-tile w, full K) -- j-invariant
    bf8v bfr[16];
#pragma unroll
    for (int s = 0; s < 16; ++s)
        bfr[s] = *(const bf8v*)&Wt[(size_t)(16 * w + lr) * 512 + 32 * s + 8 * lg];

    f4v gacc[2];
#pragma unroll
    for (int i = 0; i < 2; ++i) gacc[i] = (f4v)0.f;

    const float* xb = x + (size_t)b * (C_ * T_);

    for (int j = 0; j < 4; ++j) {
        // ---- stage chunk: all 64 channels x t-window [128j,128j+128) ----
#pragma unroll
        for (int it = 0; it < 4; ++it) {
            int i = t + 512 * it;              // 2048 float4s
            int c = i >> 5, t4 = i & 31;
            float4 v = *(const float4*)&xb[(size_t)c * T_ + 128 * j + 4 * t4];
            ushort_ h0 = f2bf(v.x), h1 = f2bf(v.y), h2 = f2bf(v.z), h3 = f2bf(v.w);
            uint2 ph;
            ph.x = (uint_)h0 | ((uint_)h1 << 16);
            ph.y = (uint_)h2 | ((uint_)h3 << 16);
            float e0 = v.x - bf2f(h0), e1 = v.y - bf2f(h1);
            float e2 = v.z - bf2f(h2), e3 = v.w - bf2f(h3);
            uint2 pl;
            pl.x = (uint_)f2bf(e0) | ((uint_)f2bf(e1) << 16);
            pl.y = (uint_)f2bf(e2) | ((uint_)f2bf(e3) << 16);
            *(uint2*)&Xh[c * 136 + 4 * t4] = ph;
            *(uint2*)&Xl[c * 136 + 4 * t4] = pl;
        }
        __syncthreads();

        // ---- gram MFMA (round-8 verified) ----
#pragma unroll
        for (int s = 0; s < 4; ++s) {
            bf8v ah = *(const bf8v*)&Xh[(16 * rp + lr) * 136 + 32 * s + 8 * lg];
            bf8v al = *(const bf8v*)&Xl[(16 * rp + lr) * 136 + 32 * s + 8 * lg];
#pragma unroll
            for (int i = 0; i < 2; ++i) {
                const int ct = 2 * ch + i;
                bf8v bh = *(const bf8v*)&Xh[(16 * ct + lr) * 136 + 32 * s + 8 * lg];
                bf8v bl = *(const bf8v*)&Xl[(16 * ct + lr) * 136 + 32 * s + 8 * lg];
                gacc[i] = __builtin_amdgcn_mfma_f32_16x16x32_bf16(ah, bh, gacc[i], 0, 0, 0);
                gacc[i] = __builtin_amdgcn_mfma_f32_16x16x32_bf16(ah, bl, gacc[i], 0, 0, 0);
                gacc[i] = __builtin_amdgcn_mfma_f32_16x16x32_bf16(al, bh, gacc[i], 0, 0, 0);
            }
        }

        // ---- layer-1 GEMM: rows [16j,16j+16), f-tile w, full K from regs ----
        {
            f4v ga = (f4v)0.f;
#pragma unroll
            for (int s = 0; s < 16; ++s) {
                bf8v af = *(const bf8v*)&Xh[(4 * s + lg) * 136 + 8 * lr];
                ga = __builtin_amdgcn_mfma_f32_16x16x32_bf16(af, bfr[s], ga, 0, 0, 0);
            }
            ushort_ yb[4];
#pragma unroll
            for (int reg = 0; reg < 4; ++reg) yb[reg] = f2bf(ga[reg]);
            *(uint2*)&Y1t[((size_t)b * 128 + 16 * w + lr) * 64 + 16 * j + 4 * lg] =
                *(uint2*)yb;
        }
        __syncthreads();
    }

    // ---- gram diagonal / norms / normalized partial store (round-8) ----
    {
        const int di = rp - 2 * ch;
        if ((di == 0 || di == 1) && lg == (lr >> 2))
            gd[16 * rp + lr] = gacc[di][lr & 3];
    }
    __syncthreads();
    if (t < 64) rn[t] = 1.0 / fmax(sqrt((double)gd[t]), 1e-12);
    __syncthreads();

    float* sp = simpart + (size_t)b * 4096;
#pragma unroll
    for (int i = 0; i < 2; ++i)
#pragma unroll
        for (int reg = 0; reg < 4; ++reg) {
            int rc = 16 * rp + 4 * lg + reg;
            int cc = 16 * (2 * ch + i) + lr;
            sp[rc * 64 + cc] = (float)((double)gacc[i][reg] * rn[rc] * rn[cc]);
        }
}

// ---------------------------------------------------------------------------
// Kernel 2: fused batch-reduction + rank-select top-K (1024 threads).
// ---------------------------------------------------------------------------
__global__ __launch_bounds__(1024) void k_simrank(const float* __restrict__ simpart,
                                                  ull_* __restrict__ masks)
{
    __shared__ double part[16][64];
    __shared__ double sd[64];
    const int c = blockIdx.x;
    const int t = threadIdx.x;
    const int d = t & 63, g = t >> 6;

    double a = 0.0;
    const float* sp = simpart + (size_t)c * 64 + d;
    for (int i = 0; i < 32; ++i)
        a += (double)sp[(size_t)(g + 16 * i) * 4096];
    part[g][d] = a;
    __syncthreads();

    if (t < 64) {
        double s = 0.0;
#pragma unroll
        for (int q = 0; q < 16; ++q) s += part[q][t];
        sd[t] = s;
        int rank = 0;
#pragma unroll
        for (int dp = 0; dp < 64; ++dp) {
            double w = sd[dp];
            rank += (w > s || (w == s && dp < t)) ? 1 : 0;
        }
        ull_ m = __ballot(rank < 16);
        if (t == 0) masks[c] = m;
    }
}

// ---------------------------------------------------------------------------
// Shared MFMA epilogue (round-8 verified): Z = M@Y + bias, BN partials to
// bnpart, Z -> global bf16.
// ---------------------------------------------------------------------------
__device__ __forceinline__ void mfma_epilogue(char* smem, int b, int t,
    f4v acc[8], const float* __restrict__ bias, const uint_ m8[8],
    ushort_* __restrict__ Zout, float* __restrict__ bnpart)
{
    const int l = t & 63, w = t >> 6;
    const int lr = l & 15, lg = l >> 4;

    ushort_* Yt  = (ushort_*)smem;             // [128][88]
    ushort_* Ml  = (ushort_*)(smem + 22528);   // [64][88]
    ushort_* Zst = (ushort_*)(smem + 33792);   // [64][136]

#pragma unroll
    for (int nt = 0; nt < 8; ++nt) {
        uint2 p;
        p.x = (uint_)f2bf(acc[nt][0]) | ((uint_)f2bf(acc[nt][1]) << 16);
        p.y = (uint_)f2bf(acc[nt][2]) | ((uint_)f2bf(acc[nt][3]) << 16);
        *(uint2*)&Yt[(16 * nt + lr) * 88 + 16 * w + 4 * lg] = p;
    }
    {
        const int d = t >> 2, q = t & 3;
        uint4 v0 = {m8[0], m8[1], m8[2], m8[3]};
        uint4 v1 = {m8[4], m8[5], m8[6], m8[7]};
        *(uint4*)&Ml[d * 88 + 16 * q]     = v0;
        *(uint4*)&Ml[d * 88 + 16 * q + 8] = v1;
    }
    __syncthreads();

    f4v z[8];
#pragma unroll
    for (int nt = 0; nt < 8; ++nt) z[nt] = (f4v)0.f;
#pragma unroll
    for (int cs = 0; cs < 2; ++cs) {
        bf8v mf = *(const bf8v*)&Ml[(16 * w + lr) * 88 + 32 * cs + 8 * lg];
#pragma unroll
        for (int nt = 0; nt < 8; ++nt) {
            bf8v yf = *(const bf8v*)&Yt[(16 * nt + lr) * 88 + 32 * cs + 8 * lg];
            z[nt] = __builtin_amdgcn_mfma_f32_16x16x32_bf16(mf, yf, z[nt], 0, 0, 0);
        }
    }

#pragma unroll
    for (int nt = 0; nt < 8; ++nt) {
        float bv = bias[16 * nt + lr];
#pragma unroll
        for (int reg = 0; reg < 4; ++reg)
            Zst[(16 * w + 4 * lg + reg) * 136 + 16 * nt + lr] = f2bf(z[nt][reg] + bv);
    }
    __syncthreads();

    if (t < 128) {
        float s = 0.f, s2 = 0.f;
        for (int r = 0; r < 64; ++r) {
            float v = bf2f(Zst[r * 136 + t]);
            s += v; s2 += v * v;
        }
        bnpart[b * 256 + t]       = s;
        bnpart[b * 256 + 128 + t] = s2;
    }
#pragma unroll
    for (int it = 0; it < 4; ++it) {
        int i = t + 256 * it;
        int r = i >> 4, seg = i & 15;
        *(uint4*)&Zout[((size_t)(b * 64 + r)) * 128 + 8 * seg] =
            *(const uint4*)&Zst[r * 136 + 8 * seg];
    }
}

// ---------------------------------------------------------------------------
// Kernel 3: mix layer 1 -> Z1 = M @ Y1 + b1 (r9-validated, r8 BN tail).
// ---------------------------------------------------------------------------
__global__ __launch_bounds__(256) void k_mix1(const ushort_* __restrict__ Y1t,
    const float* __restrict__ bias, const ull_* __restrict__ masks,
    ushort_* __restrict__ Zout, float* __restrict__ bnpart)
{
    __shared__ __align__(16) char smem[51200];
    __shared__ ull_  nbrmS[64];
    __shared__ float dvS[64];
    ushort_* Yt = (ushort_*)smem;              // [128][88]

    const int b = blockIdx.x;
    const int t = threadIdx.x;

    m_preamble_wave0(masks, nbrmS, dvS, t);

    // stage Y^T from global into Yt[f][r] (stride 88)
#pragma unroll
    for (int it = 0; it < 8; ++it) {
        int i = t + 256 * it;                 // 2048 uint4
        int f = i >> 3, seg = i & 7;
        *(uint4*)&Yt[f * 88 + 8 * seg] =
            *(const uint4*)&Y1t[(size_t)b * 8192 + f * 64 + 8 * seg];
    }
    __syncthreads();

    // acc = Y fragments read back from Yt (mfma_epilogue re-stores them,
    // which is redundant but keeps the verified code path intact)
    const int l = t & 63, w = t >> 6;
    const int lr = l & 15, lg = l >> 4;
    f4v acc[8];
#pragma unroll
    for (int nt = 0; nt < 8; ++nt) {
        uint2 p = *(const uint2*)&Yt[(16 * nt + lr) * 88 + 16 * w + 4 * lg];
        acc[nt][0] = bf2f((ushort_)(p.x & 0xFFFF));
        acc[nt][1] = bf2f((ushort_)(p.x >> 16));
        acc[nt][2] = bf2f((ushort_)(p.y & 0xFFFF));
        acc[nt][3] = bf2f((ushort_)(p.y >> 16));
    }
    __syncthreads();

    uint_ m8[8];
    m_build(nbrmS, dvS, t, m8);
    mfma_epilogue(smem, b, t, acc, bias, m8, Zout, bnpart);
}

// ---------------------------------------------------------------------------
// Layers 2/3: inline BN-finalize (from bnp2) + inline-M + GEMM (round-8).
// ---------------------------------------------------------------------------
__global__ __launch_bounds__(256) void k_mgemm23(const ushort_* __restrict__ Zin,
    const double* __restrict__ bnp2, const float* __restrict__ g,
    const float* __restrict__ be, const ushort_* __restrict__ Wt,
    const float* __restrict__ bias, const ull_* __restrict__ masks,
    ushort_* __restrict__ Zout, float* __restrict__ bnpart)
{
    __shared__ __align__(16) char smem[52224];
    __shared__ float ssL[256];
    __shared__ ull_  nbrmS[64];
    __shared__ float dvS[64];
    ushort_* Al = (ushort_*)smem;              // [64][136]
    ushort_* Wl = (ushort_*)(smem + 17408);    // [128][128]

    const int b = blockIdx.x;
    const int t = threadIdx.x;
    const int l = t & 63, w = t >> 6;
    const int lr = l & 15, lg = l >> 4;

    // --- BN finalize preamble (sums overlay Al region temporarily) ---
    {
        double* sumsL = (double*)smem;
        double a = 0.0;
        for (int q = 0; q < 32; ++q) a += bnp2[(size_t)q * 256 + t];
        sumsL[t] = a;
        m_preamble_wave0(masks, nbrmS, dvS, t);
        __syncthreads();
        if (t < 128) {
            double s = sumsL[t], s2 = sumsL[128 + t];
            double mean = s * (1.0 / 32768.0);
            double var  = s2 * (1.0 / 32768.0) - mean * mean;
            double rstd = 1.0 / sqrt(var + 1e-5);
            float sc = (float)((double)g[t] * rstd);
            ssL[t]       = sc;
            ssL[128 + t] = (float)((double)be[t] - mean * (double)sc);
        }
        __syncthreads();
    }

    // W: linear 32 KB DMA (overlaps the A-staging VALU below)
    {
        const char* wsrc = (const char*)Wt + t * 16;
        char* wdst = smem + 17408 + t * 16;
#pragma unroll
        for (int i2 = 0; i2 < 8; ++i2)
            gload_lds16(wsrc + i2 * 4096, wdst + i2 * 4096);
    }

    f4v acc[8];
#pragma unroll
    for (int nt = 0; nt < 8; ++nt) acc[nt] = (f4v)0.f;

    // stage A with BN fold + relu
#pragma unroll
    for (int it = 0; it < 4; ++it) {
        int i = t + 256 * it;
        int r = i >> 4, seg = i & 15;
        uint4 v = *(const uint4*)&Zin[((size_t)(b * 64 + r)) * 128 + 8 * seg];
        uint_ w0[4] = {v.x, v.y, v.z, v.w};
        uint_ o[4];
#pragma unroll
        for (int p = 0; p < 4; ++p) {
            int f0 = 8 * seg + 2 * p;
            float z0 = bf2f((ushort_)(w0[p] & 0xFFFF));
            float z1 = bf2f((ushort_)(w0[p] >> 16));
            float h0 = fmaxf(fmaf(z0, ssL[f0],     ssL[128 + f0]),     0.f);
            float h1 = fmaxf(fmaf(z1, ssL[f0 + 1], ssL[128 + f0 + 1]), 0.f);
            o[p] = (uint_)f2bf(h0) | ((uint_)f2bf(h1) << 16);
        }
        uint4 ov = {o[0], o[1], o[2], o[3]};
        *(uint4*)&Al[r * 136 + 8 * seg] = ov;
    }
    __syncthreads();
#pragma unroll
    for (int s = 0; s < 4; ++s) {
        bf8v af = *(const bf8v*)&Al[(16 * w + lr) * 136 + 32 * s + 8 * lg];
#pragma unroll
        for (int nt = 0; nt < 8; ++nt) {
            bf8v bfv = *(const bf8v*)&Wl[(16 * nt + lr) * 128 + 32 * s + 8 * lg];
            acc[nt] = __builtin_amdgcn_mfma_f32_16x16x32_bf16(af, bfv, acc[nt], 0, 0, 0);
        }
    }
    __syncthreads();

    uint_ m8[8];
    m_build(nbrmS, dvS, t, m8);
    mfma_epilogue(smem, b, t, acc, bias, m8, Zout, bnpart);
}

// ---------------------------------------------------------------------------
// BN reduce stage A: 32 blocks, 512 -> 32 partials in f64.
// ---------------------------------------------------------------------------
__global__ __launch_bounds__(256) void k_bnA(const float* __restrict__ bnpart,
                                             double* __restrict__ bnp2)
{
    const int t = threadIdx.x, g = blockIdx.x;
    double a = 0.0;
    for (int i = 0; i < 16; ++i)
        a += (double)bnpart[(size_t)(16 * g + i) * 256 + t];
    bnp2[(size_t)g * 256 + t] = a;
}

// ---------------------------------------------------------------------------
// Final BN + ReLU with inline BN-finalize (round-8).
// ---------------------------------------------------------------------------
__global__ __launch_bounds__(256) void k_out(const ushort_* __restrict__ Z,
    const double* __restrict__ bnp2, const float* __restrict__ g,
    const float* __restrict__ be, float* __restrict__ out)
{
    __shared__ double sumsL[256];
    __shared__ float  ssL[256];
    const int b = blockIdx.x;
    const int t = threadIdx.x;

    double a = 0.0;
    for (int q = 0; q < 32; ++q) a += bnp2[(size_t)q * 256 + t];
    sumsL[t] = a;
    __syncthreads();
    if (t < 128) {
        double s = sumsL[t], s2 = sumsL[128 + t];
        double mean = s * (1.0 / 32768.0);
        double var  = s2 * (1.0 / 32768.0) - mean * mean;
        double rstd = 1.0 / sqrt(var + 1e-5);
        float sc = (float)((double)g[t] * rstd);
        ssL[t]       = sc;
        ssL[128 + t] = (float)((double)be[t] - mean * (double)sc);
    }
    __syncthreads();

    const size_t base = (size_t)b * 64 * 128;
#pragma unroll
    for (int it = 0; it < 8; ++it) {
        int i = t + 256 * it;
        int r = i >> 5, s = i & 31;
        uint2 v = *(const uint2*)&Z[base + (size_t)r * 128 + 4 * s];
        float4 sc = *(const float4*)&ssL[4 * s];
        float4 sh = *(const float4*)&ssL[128 + 4 * s];
        float z0 = bf2f((ushort_)(v.x & 0xFFFF));
        float z1 = bf2f((ushort_)(v.x >> 16));
        float z2 = bf2f((ushort_)(v.y & 0xFFFF));
        float z3 = bf2f((ushort_)(v.y >> 16));
        float4 o;
        o.x = fmaxf(fmaf(z0, sc.x, sh.x), 0.f);
        o.y = fmaxf(fmaf(z1, sc.y, sh.y), 0.f);
        o.z = fmaxf(fmaf(z2, sc.z, sh.z), 0.f);
        o.w = fmaxf(fmaf(z3, sc.w, sh.w), 0.f);
        *(float4*)&out[base + (size_t)r * 128 + 4 * s] = o;
    }
}

// ---------------------------------------------------------------------------
extern "C" void kernel_launch(void* const* d_in, const int* in_sizes, int n_in,
                              void* d_out, int out_size, void* d_ws, size_t ws_size,
                              hipStream_t stream)
{
    (void)in_sizes; (void)n_in; (void)out_size; (void)ws_size;

    const float* x   = (const float*)d_in[0];
    const float* W1  = (const float*)d_in[9];
    const float* b1  = (const float*)d_in[10];
    const float* g1  = (const float*)d_in[11];
    const float* be1 = (const float*)d_in[12];
    const float* W2  = (const float*)d_in[13];
    const float* b2  = (const float*)d_in[14];
    const float* g2  = (const float*)d_in[15];
    const float* be2 = (const float*)d_in[16];
    const float* W3  = (const float*)d_in[17];
    const float* b3  = (const float*)d_in[18];
    const float* g3  = (const float*)d_in[19];
    const float* be3 = (const float*)d_in[20];

    char* ws = (char*)d_ws;
    float*   simp   = (float*)(ws + OFF_SIMP);
    ull_*    masks  = (ull_*)(ws + OFF_MASKS);
    ushort_* Wt1    = (ushort_*)(ws + OFF_WT1);
    ushort_* Wt2    = (ushort_*)(ws + OFF_WT2);
    ushort_* Wt3    = (ushort_*)(ws + OFF_WT3);
    float*   bnpart = (float*)(ws + OFF_BNPART);
    double*  bnp2   = (double*)(ws + OFF_BNP2);
    ushort_* Y1t    = (ushort_*)(ws + OFF_Y1T);
    ushort_* Z1     = (ushort_*)(ws + OFF_Z1);
    ushort_* Z2     = (ushort_*)(ws + OFF_Z2);   // reuses simp region
    ushort_* Z3     = (ushort_*)(ws + OFF_Z3);
    float*   out    = (float*)d_out;

    k_prepw<<<dim3(12), dim3(256), 0, stream>>>(W1, W2, W3, Wt1, Wt2, Wt3);
    k_gramg1<<<dim3(512), dim3(512), 0, stream>>>(x, simp, Wt1, Y1t);
    k_simrank<<<dim3(64), dim3(1024), 0, stream>>>(simp, masks);

    k_mix1<<<dim3(512), dim3(256), 0, stream>>>(Y1t, b1, masks, Z1, bnpart);
    k_bnA<<<dim3(32), dim3(256), 0, stream>>>(bnpart, bnp2);

    k_mgemm23<<<dim3(512), dim3(256), 0, stream>>>(Z1, bnp2, g1, be1, Wt2, b2, masks, Z2, bnpart);
    k_bnA<<<dim3(32), dim3(256), 0, stream>>>(bnpart, bnp2);

    k_mgemm23<<<dim3(512), dim3(256), 0, stream>>>(Z2, bnp2, g2, be2, Wt3, b3, masks, Z3, bnpart);
    k_bnA<<<dim3(32), dim3(256), 0, stream>>>(bnpart, bnp2);

    k_out<<<dim3(512), dim3(256), 0, stream>>>(Z3, bnp2, g3, be3, out);
}

// Round 13
// 90.386 us; speedup vs baseline: 1.4337x; 1.0342x over previous
//
#include <hip/hip_runtime.h>
#include <math.h>

// Problem constants
#define B_  512
#define C_  64
#define T_  512
#define H_  128
#define N_  (B_*C_)   // 32768

typedef unsigned int   uint_;
typedef unsigned short ushort_;
typedef unsigned long long ull_;

typedef __attribute__((ext_vector_type(8))) short bf8v;   // 8 bf16 (4 VGPRs)
typedef __attribute__((ext_vector_type(4))) float f4v;    // MFMA accumulator

// Workspace byte offsets
#define OFF_SIMP   0u            // 512*4096*4 = 8,388,608 ; reused as Z2 later
#define OFF_Z2     0u
#define OFF_Z1     8388608u      // 8,388,608 (bf16 32768x128)
#define OFF_Z3     16777216u     // 8,388,608
#define OFF_WT1    25165824u     // 128*512*2 = 131,072
#define OFF_WT2    25296896u     // 32,768
#define OFF_WT3    25329664u     // 32,768
#define OFF_MASKS  25362432u     // 64*8 = 512
#define OFF_BNPART 25406464u     // 512*256*4 = 524,288 -> end 25,930,752
#define OFF_BNP2   25930752u     // 32*256*8  = 65,536  -> end 25,996,288
#define OFF_Y1T    33554432u     // 512*128*64*2 = 8,388,608

__device__ __forceinline__ ushort_ f2bf(float f) {
    uint_ u = __float_as_uint(f);
    u = (u + 0x7FFFu + ((u >> 16) & 1u)) >> 16;    // RNE (finite values only)
    return (ushort_)u;
}
__device__ __forceinline__ float bf2f(ushort_ s) {
    return __uint_as_float(((uint_)s) << 16);
}

// global -> LDS direct DMA, 16 bytes per lane (wave-uniform base + lane*16).
__device__ __forceinline__ void gload_lds16(const void* g, void* l) {
    __builtin_amdgcn_global_load_lds(
        (const __attribute__((address_space(1))) void*)g,
        (__attribute__((address_space(3))) void*)l, 16, 0, 0);
}

// ---------------------------------------------------------------------------
// Graph-matrix helpers.
// ---------------------------------------------------------------------------
__device__ __forceinline__ void m_preamble_wave0(const ull_* __restrict__ masks,
                                                 ull_* nbrmS, float* dvS, int t)
{
    if (t < 64) {
        ull_ mask = masks[t];
        nbrmS[t] = mask;
        int deg = 1;                   // self-loop
#pragma unroll
        for (int d = 0; d < 64; ++d) {
            ull_ bal = __ballot((int)((mask >> d) & 1ull));
            if (t == d) deg += (int)__popcll(bal);
        }
        dvS[t] = 1.0f / sqrtf((float)deg);
    }
}

__device__ __forceinline__ void m_build(const ull_* nbrmS, const float* dvS,
                                        int t, uint_ m8[8])
{
    const int d = t >> 2, q = t & 3;
    const float dvd = dvS[d];
#pragma unroll
    for (int p = 0; p < 8; ++p) {
        int c0 = 16 * q + 2 * p, c1 = c0 + 1;
        float w0 = (float)((int)((nbrmS[c0] >> d) & 1ull) + (c0 == d ? 1 : 0));
        float w1 = (float)((int)((nbrmS[c1] >> d) & 1ull) + (c1 == d ? 1 : 0));
        m8[p] = (uint_)f2bf(w0 * dvS[c0] * dvd) |
                ((uint_)f2bf(w1 * dvS[c1] * dvd) << 16);
    }
}

// ---------------------------------------------------------------------------
// Weight prep (standalone, must precede k_gramg1 which reads Wt1).
// ---------------------------------------------------------------------------
__global__ __launch_bounds__(256) void k_prepw(const float* __restrict__ W1,
    const float* __restrict__ W2, const float* __restrict__ W3,
    ushort_* __restrict__ Wt1, ushort_* __restrict__ Wt2, ushort_* __restrict__ Wt3)
{
    __shared__ float L[64 * 132];
    const int blk = blockIdx.x, t = threadIdx.x;

    if (blk < 8) {
        for (int it = 0; it < 8; ++it) {
            int i = t + 256 * it;
            int ri = i >> 5, f4 = i & 31;
            int m = ri >> 3, cr = ri & 7;
            *(float4*)&L[ri * 132 + 4 * f4] =
                *(const float4*)&W1[(size_t)(64 * m + 8 * blk + cr) * H_ + 4 * f4];
        }
        __syncthreads();
        int f = t >> 1, half = t & 1;
        uint_ buf[16];
#pragma unroll
        for (int jj = 0; jj < 16; ++jj) {
            int k0 = 32 * half + 2 * jj;
            int c0 = k0 >> 3, m0 = k0 & 7;
            int c1 = (k0 + 1) >> 3, m1 = (k0 + 1) & 7;
            buf[jj] = (uint_)f2bf(L[(m0 * 8 + c0) * 132 + f]) |
                      ((uint_)f2bf(L[(m1 * 8 + c1) * 132 + f]) << 16);
        }
        ushort_* dst = Wt1 + (size_t)f * 512 + 64 * blk + 32 * half;
#pragma unroll
        for (int q = 0; q < 4; ++q) {
            uint4 vv = {buf[4 * q], buf[4 * q + 1], buf[4 * q + 2], buf[4 * q + 3]};
            *(uint4*)&dst[8 * q] = vv;
        }
    } else {
        const float* W = (blk < 10) ? W2 : W3;
        ushort_*     O = (blk < 10) ? Wt2 : Wt3;
        int kb = (blk - 8) & 1;
        for (int it = 0; it < 8; ++it) {
            int i = t + 256 * it;
            int ri = i >> 5, f4 = i & 31;
            *(float4*)&L[ri * 132 + 4 * f4] =
                *(const float4*)&W[(size_t)(64 * kb + ri) * H_ + 4 * f4];
        }
        __syncthreads();
        int f = t >> 1, half = t & 1;
        uint_ buf[16];
#pragma unroll
        for (int jj = 0; jj < 16; ++jj) {
            int k0 = 32 * half + 2 * jj;
            buf[jj] = (uint_)f2bf(L[k0 * 132 + f]) |
                      ((uint_)f2bf(L[(k0 + 1) * 132 + f]) << 16);
        }
        ushort_* dst = O + (size_t)f * 128 + 64 * kb + 32 * half;
#pragma unroll
        for (int q = 0; q < 4; ++q) {
            uint4 vv = {buf[4 * q], buf[4 * q + 1], buf[4 * q + 2], buf[4 * q + 3]};
            *(uint4*)&dst[8 * q] = vv;
        }
    }
}

// ---------------------------------------------------------------------------
// Kernel 1 (FUSED gram + layer-1 GEMM, software-pipelined staging).
// vbuf holds chunk j+1's global data in registers, issued right after the
// first barrier so HBM latency drains under chunk j's 40 MFMAs (T14).
// Arithmetic order identical to round 12 -> bit-identical sim and Y1.
// ---------------------------------------------------------------------------
__global__ __launch_bounds__(512, 4) void k_gramg1(const float* __restrict__ x,
    float* __restrict__ simpart, const ushort_* __restrict__ Wt,
    ushort_* __restrict__ Y1t)
{
    __shared__ ushort_ Xh[64 * 136];
    __shared__ ushort_ Xl[64 * 136];
    __shared__ float  gd[64];
    __shared__ double rn[64];

    const int b = blockIdx.x;
    const int t = threadIdx.x;
    const int w = t >> 6, l = t & 63;
    const int lr = l & 15, lg = l >> 4;
    const int rp = w >> 1, ch = w & 1;         // gram row-tile, col-half

    // preload the wave's 16 B-fragments (f-tile w, full K) -- j-invariant
    bf8v bfr[16];
#pragma unroll
    for (int s = 0; s < 16; ++s)
        bfr[s] = *(const bf8v*)&Wt[(size_t)(16 * w + lr) * 512 + 32 * s + 8 * lg];

    f4v gacc[2];
#pragma unroll
    for (int i = 0; i < 2; ++i) gacc[i] = (f4v)0.f;

    const float* xb = x + (size_t)b * (C_ * T_);

    // prologue: chunk 0 into registers
    float4 vbuf[4];
#pragma unroll
    for (int it = 0; it < 4; ++it) {
        int i = t + 512 * it;
        int c = i >> 5, t4 = i & 31;
        vbuf[it] = *(const float4*)&xb[(size_t)c * T_ + 4 * t4];
    }

    for (int j = 0; j < 4; ++j) {
        // ---- convert + LDS write from registers ----
#pragma unroll
        for (int it = 0; it < 4; ++it) {
            int i = t + 512 * it;
            int c = i >> 5, t4 = i & 31;
            float4 v = vbuf[it];
            ushort_ h0 = f2bf(v.x), h1 = f2bf(v.y), h2 = f2bf(v.z), h3 = f2bf(v.w);
            uint2 ph;
            ph.x = (uint_)h0 | ((uint_)h1 << 16);
            ph.y = (uint_)h2 | ((uint_)h3 << 16);
            float e0 = v.x - bf2f(h0), e1 = v.y - bf2f(h1);
            float e2 = v.z - bf2f(h2), e3 = v.w - bf2f(h3);
            uint2 pl;
            pl.x = (uint_)f2bf(e0) | ((uint_)f2bf(e1) << 16);
            pl.y = (uint_)f2bf(e2) | ((uint_)f2bf(e3) << 16);
            *(uint2*)&Xh[c * 136 + 4 * t4] = ph;
            *(uint2*)&Xl[c * 136 + 4 * t4] = pl;
        }
        __syncthreads();

        // ---- issue next chunk's loads (drain under the MFMAs below) ----
        if (j < 3) {
#pragma unroll
            for (int it = 0; it < 4; ++it) {
                int i = t + 512 * it;
                int c = i >> 5, t4 = i & 31;
                vbuf[it] = *(const float4*)&xb[(size_t)c * T_ + 128 * (j + 1) + 4 * t4];
            }
        }

        // ---- gram MFMA (round-8 verified) ----
#pragma unroll
        for (int s = 0; s < 4; ++s) {
            bf8v ah = *(const bf8v*)&Xh[(16 * rp + lr) * 136 + 32 * s + 8 * lg];
            bf8v al = *(const bf8v*)&Xl[(16 * rp + lr) * 136 + 32 * s + 8 * lg];
#pragma unroll
            for (int i = 0; i < 2; ++i) {
                const int ct = 2 * ch + i;
                bf8v bh = *(const bf8v*)&Xh[(16 * ct + lr) * 136 + 32 * s + 8 * lg];
                bf8v bl = *(const bf8v*)&Xl[(16 * ct + lr) * 136 + 32 * s + 8 * lg];
                gacc[i] = __builtin_amdgcn_mfma_f32_16x16x32_bf16(ah, bh, gacc[i], 0, 0, 0);
                gacc[i] = __builtin_amdgcn_mfma_f32_16x16x32_bf16(ah, bl, gacc[i], 0, 0, 0);
                gacc[i] = __builtin_amdgcn_mfma_f32_16x16x32_bf16(al, bh, gacc[i], 0, 0, 0);
            }
        }

        // ---- layer-1 GEMM: rows [16j,16j+16), f-tile w, full K from regs ----
        {
            f4v ga = (f4v)0.f;
#pragma unroll
            for (int s = 0; s < 16; ++s) {
                bf8v af = *(const bf8v*)&Xh[(4 * s + lg) * 136 + 8 * lr];
                ga = __builtin_amdgcn_mfma_f32_16x16x32_bf16(af, bfr[s], ga, 0, 0, 0);
            }
            ushort_ yb[4];
#pragma unroll
            for (int reg = 0; reg < 4; ++reg) yb[reg] = f2bf(ga[reg]);
            *(uint2*)&Y1t[((size_t)b * 128 + 16 * w + lr) * 64 + 16 * j + 4 * lg] =
                *(uint2*)yb;
        }
        __syncthreads();
    }

    // ---- gram diagonal / norms / normalized partial store (round-8) ----
    {
        const int di = rp - 2 * ch;
        if ((di == 0 || di == 1) && lg == (lr >> 2))
            gd[16 * rp + lr] = gacc[di][lr & 3];
    }
    __syncthreads();
    if (t < 64) rn[t] = 1.0 / fmax(sqrt((double)gd[t]), 1e-12);
    __syncthreads();

    float* sp = simpart + (size_t)b * 4096;
#pragma unroll
    for (int i = 0; i < 2; ++i)
#pragma unroll
        for (int reg = 0; reg < 4; ++reg) {
            int rc = 16 * rp + 4 * lg + reg;
            int cc = 16 * (2 * ch + i) + lr;
            sp[rc * 64 + cc] = (float)((double)gacc[i][reg] * rn[rc] * rn[cc]);
        }
}

// ---------------------------------------------------------------------------
// Kernel 2: fused batch-reduction + rank-select top-K (1024 threads).
// ---------------------------------------------------------------------------
__global__ __launch_bounds__(1024) void k_simrank(const float* __restrict__ simpart,
                                                  ull_* __restrict__ masks)
{
    __shared__ double part[16][64];
    __shared__ double sd[64];
    const int c = blockIdx.x;
    const int t = threadIdx.x;
    const int d = t & 63, g = t >> 6;

    double a = 0.0;
    const float* sp = simpart + (size_t)c * 64 + d;
    for (int i = 0; i < 32; ++i)
        a += (double)sp[(size_t)(g + 16 * i) * 4096];
    part[g][d] = a;
    __syncthreads();

    if (t < 64) {
        double s = 0.0;
#pragma unroll
        for (int q = 0; q < 16; ++q) s += part[q][t];
        sd[t] = s;
        int rank = 0;
#pragma unroll
        for (int dp = 0; dp < 64; ++dp) {
            double w = sd[dp];
            rank += (w > s || (w == s && dp < t)) ? 1 : 0;
        }
        ull_ m = __ballot(rank < 16);
        if (t == 0) masks[c] = m;
    }
}

// ---------------------------------------------------------------------------
// Shared MFMA epilogue (round-8 verified): Z = M@Y + bias, BN partials to
// bnpart, Z -> global bf16.
// ---------------------------------------------------------------------------
__device__ __forceinline__ void mfma_epilogue(char* smem, int b, int t,
    f4v acc[8], const float* __restrict__ bias, const uint_ m8[8],
    ushort_* __restrict__ Zout, float* __restrict__ bnpart)
{
    const int l = t & 63, w = t >> 6;
    const int lr = l & 15, lg = l >> 4;

    ushort_* Yt  = (ushort_*)smem;             // [128][88]
    ushort_* Ml  = (ushort_*)(smem + 22528);   // [64][88]
    ushort_* Zst = (ushort_*)(smem + 33792);   // [64][136]

#pragma unroll
    for (int nt = 0; nt < 8; ++nt) {
        uint2 p;
        p.x = (uint_)f2bf(acc[nt][0]) | ((uint_)f2bf(acc[nt][1]) << 16);
        p.y = (uint_)f2bf(acc[nt][2]) | ((uint_)f2bf(acc[nt][3]) << 16);
        *(uint2*)&Yt[(16 * nt + lr) * 88 + 16 * w + 4 * lg] = p;
    }
    {
        const int d = t >> 2, q = t & 3;
        uint4 v0 = {m8[0], m8[1], m8[2], m8[3]};
        uint4 v1 = {m8[4], m8[5], m8[6], m8[7]};
        *(uint4*)&Ml[d * 88 + 16 * q]     = v0;
        *(uint4*)&Ml[d * 88 + 16 * q + 8] = v1;
    }
    __syncthreads();

    f4v z[8];
#pragma unroll
    for (int nt = 0; nt < 8; ++nt) z[nt] = (f4v)0.f;
#pragma unroll
    for (int cs = 0; cs < 2; ++cs) {
        bf8v mf = *(const bf8v*)&Ml[(16 * w + lr) * 88 + 32 * cs + 8 * lg];
#pragma unroll
        for (int nt = 0; nt < 8; ++nt) {
            bf8v yf = *(const bf8v*)&Yt[(16 * nt + lr) * 88 + 32 * cs + 8 * lg];
            z[nt] = __builtin_amdgcn_mfma_f32_16x16x32_bf16(mf, yf, z[nt], 0, 0, 0);
        }
    }

#pragma unroll
    for (int nt = 0; nt < 8; ++nt) {
        float bv = bias[16 * nt + lr];
#pragma unroll
        for (int reg = 0; reg < 4; ++reg)
            Zst[(16 * w + 4 * lg + reg) * 136 + 16 * nt + lr] = f2bf(z[nt][reg] + bv);
    }
    __syncthreads();

    if (t < 128) {
        float s = 0.f, s2 = 0.f;
        for (int r = 0; r < 64; ++r) {
            float v = bf2f(Zst[r * 136 + t]);
            s += v; s2 += v * v;
        }
        bnpart[b * 256 + t]       = s;
        bnpart[b * 256 + 128 + t] = s2;
    }
#pragma unroll
    for (int it = 0; it < 4; ++it) {
        int i = t + 256 * it;
        int r = i >> 4, seg = i & 15;
        *(uint4*)&Zout[((size_t)(b * 64 + r)) * 128 + 8 * seg] =
            *(const uint4*)&Zst[r * 136 + 8 * seg];
    }
}

// ---------------------------------------------------------------------------
// Kernel 3: mix layer 1 -> Z1 = M @ Y1 + b1.
// ---------------------------------------------------------------------------
__global__ __launch_bounds__(256) void k_mix1(const ushort_* __restrict__ Y1t,
    const float* __restrict__ bias, const ull_* __restrict__ masks,
    ushort_* __restrict__ Zout, float* __restrict__ bnpart)
{
    __shared__ __align__(16) char smem[51200];
    __shared__ ull_  nbrmS[64];
    __shared__ float dvS[64];
    ushort_* Yt = (ushort_*)smem;              // [128][88]

    const int b = blockIdx.x;
    const int t = threadIdx.x;

    m_preamble_wave0(masks, nbrmS, dvS, t);

    // stage Y^T from global into Yt[f][r] (stride 88)
#pragma unroll
    for (int it = 0; it < 8; ++it) {
        int i = t + 256 * it;                 // 2048 uint4
        int f = i >> 3, seg = i & 7;
        *(uint4*)&Yt[f * 88 + 8 * seg] =
            *(const uint4*)&Y1t[(size_t)b * 8192 + f * 64 + 8 * seg];
    }
    __syncthreads();

    const int l = t & 63, w = t >> 6;
    const int lr = l & 15, lg = l >> 4;
    f4v acc[8];
#pragma unroll
    for (int nt = 0; nt < 8; ++nt) {
        uint2 p = *(const uint2*)&Yt[(16 * nt + lr) * 88 + 16 * w + 4 * lg];
        acc[nt][0] = bf2f((ushort_)(p.x & 0xFFFF));
        acc[nt][1] = bf2f((ushort_)(p.x >> 16));
        acc[nt][2] = bf2f((ushort_)(p.y & 0xFFFF));
        acc[nt][3] = bf2f((ushort_)(p.y >> 16));
    }
    __syncthreads();

    uint_ m8[8];
    m_build(nbrmS, dvS, t, m8);
    mfma_epilogue(smem, b, t, acc, bias, m8, Zout, bnpart);
}

// ---------------------------------------------------------------------------
// Layers 2/3: issue-early Zin loads + inline BN-finalize + inline-M + GEMM.
// ---------------------------------------------------------------------------
__global__ __launch_bounds__(256) void k_mgemm23(const ushort_* __restrict__ Zin,
    const double* __restrict__ bnp2, const float* __restrict__ g,
    const float* __restrict__ be, const ushort_* __restrict__ Wt,
    const float* __restrict__ bias, const ull_* __restrict__ masks,
    ushort_* __restrict__ Zout, float* __restrict__ bnpart)
{
    __shared__ __align__(16) char smem[52224];
    __shared__ float ssL[256];
    __shared__ ull_  nbrmS[64];
    __shared__ float dvS[64];
    ushort_* Al = (ushort_*)smem;              // [64][136]
    ushort_* Wl = (ushort_*)(smem + 17408);    // [128][128]

    const int b = blockIdx.x;
    const int t = threadIdx.x;
    const int l = t & 63, w = t >> 6;
    const int lr = l & 15, lg = l >> 4;

    // issue A-loads early: HBM latency drains under the BN preamble
    uint4 zv[4];
#pragma unroll
    for (int it = 0; it < 4; ++it) {
        int i = t + 256 * it;
        int r = i >> 4, seg = i & 15;
        zv[it] = *(const uint4*)&Zin[((size_t)(b * 64 + r)) * 128 + 8 * seg];
    }

    // --- BN finalize preamble (sums overlay Al region temporarily) ---
    {
        double* sumsL = (double*)smem;
        double a = 0.0;
        for (int q = 0; q < 32; ++q) a += bnp2[(size_t)q * 256 + t];
        sumsL[t] = a;
        m_preamble_wave0(masks, nbrmS, dvS, t);
        __syncthreads();
        if (t < 128) {
            double s = sumsL[t], s2 = sumsL[128 + t];
            double mean = s * (1.0 / 32768.0);
            double var  = s2 * (1.0 / 32768.0) - mean * mean;
            double rstd = 1.0 / sqrt(var + 1e-5);
            float sc = (float)((double)g[t] * rstd);
            ssL[t]       = sc;
            ssL[128 + t] = (float)((double)be[t] - mean * (double)sc);
        }
        __syncthreads();
    }

    // W: linear 32 KB DMA (overlaps the A-conversion VALU below)
    {
        const char* wsrc = (const char*)Wt + t * 16;
        char* wdst = smem + 17408 + t * 16;
#pragma unroll
        for (int i2 = 0; i2 < 8; ++i2)
            gload_lds16(wsrc + i2 * 4096, wdst + i2 * 4096);
    }

    f4v acc[8];
#pragma unroll
    for (int nt = 0; nt < 8; ++nt) acc[nt] = (f4v)0.f;

    // convert pre-loaded A with BN fold + relu -> Al
#pragma unroll
    for (int it = 0; it < 4; ++it) {
        int i = t + 256 * it;
        int r = i >> 4, seg = i & 15;
        uint_ w0[4] = {zv[it].x, zv[it].y, zv[it].z, zv[it].w};
        uint_ o[4];
#pragma unroll
        for (int p = 0; p < 4; ++p) {
            int f0 = 8 * seg + 2 * p;
            float z0 = bf2f((ushort_)(w0[p] & 0xFFFF));
            float z1 = bf2f((ushort_)(w0[p] >> 16));
            float h0 = fmaxf(fmaf(z0, ssL[f0],     ssL[128 + f0]),     0.f);
            float h1 = fmaxf(fmaf(z1, ssL[f0 + 1], ssL[128 + f0 + 1]), 0.f);
            o[p] = (uint_)f2bf(h0) | ((uint_)f2bf(h1) << 16);
        }
        uint4 ov = {o[0], o[1], o[2], o[3]};
        *(uint4*)&Al[r * 136 + 8 * seg] = ov;
    }
    __syncthreads();
#pragma unroll
    for (int s = 0; s < 4; ++s) {
        bf8v af = *(const bf8v*)&Al[(16 * w + lr) * 136 + 32 * s + 8 * lg];
#pragma unroll
        for (int nt = 0; nt < 8; ++nt) {
            bf8v bfv = *(const bf8v*)&Wl[(16 * nt + lr) * 128 + 32 * s + 8 * lg];
            acc[nt] = __builtin_amdgcn_mfma_f32_16x16x32_bf16(af, bfv, acc[nt], 0, 0, 0);
        }
    }
    __syncthreads();

    uint_ m8[8];
    m_build(nbrmS, dvS, t, m8);
    mfma_epilogue(smem, b, t, acc, bias, m8, Zout, bnpart);
}

// ---------------------------------------------------------------------------
// BN reduce stage A: 32 blocks, 512 -> 32 partials in f64.
// ---------------------------------------------------------------------------
__global__ __launch_bounds__(256) void k_bnA(const float* __restrict__ bnpart,
                                             double* __restrict__ bnp2)
{
    const int t = threadIdx.x, g = blockIdx.x;
    double a = 0.0;
    for (int i = 0; i < 16; ++i)
        a += (double)bnpart[(size_t)(16 * g + i) * 256 + t];
    bnp2[(size_t)g * 256 + t] = a;
}

// ---------------------------------------------------------------------------
// Final BN + ReLU with inline BN-finalize.
// ---------------------------------------------------------------------------
__global__ __launch_bounds__(256) void k_out(const ushort_* __restrict__ Z,
    const double* __restrict__ bnp2, const float* __restrict__ g,
    const float* __restrict__ be, float* __restrict__ out)
{
    __shared__ double sumsL[256];
    __shared__ float  ssL[256];
    const int b = blockIdx.x;
    const int t = threadIdx.x;

    double a = 0.0;
    for (int q = 0; q < 32; ++q) a += bnp2[(size_t)q * 256 + t];
    sumsL[t] = a;
    __syncthreads();
    if (t < 128) {
        double s = sumsL[t], s2 = sumsL[128 + t];
        double mean = s * (1.0 / 32768.0);
        double var  = s2 * (1.0 / 32768.0) - mean * mean;
        double rstd = 1.0 / sqrt(var + 1e-5);
        float sc = (float)((double)g[t] * rstd);
        ssL[t]       = sc;
        ssL[128 + t] = (float)((double)be[t] - mean * (double)sc);
    }
    __syncthreads();

    const size_t base = (size_t)b * 64 * 128;
#pragma unroll
    for (int it = 0; it < 8; ++it) {
        int i = t + 256 * it;
        int r = i >> 5, s = i & 31;
        uint2 v = *(const uint2*)&Z[base + (size_t)r * 128 + 4 * s];
        float4 sc = *(const float4*)&ssL[4 * s];
        float4 sh = *(const float4*)&ssL[128 + 4 * s];
        float z0 = bf2f((ushort_)(v.x & 0xFFFF));
        float z1 = bf2f((ushort_)(v.x >> 16));
        float z2 = bf2f((ushort_)(v.y & 0xFFFF));
        float z3 = bf2f((ushort_)(v.y >> 16));
        float4 o;
        o.x = fmaxf(fmaf(z0, sc.x, sh.x), 0.f);
        o.y = fmaxf(fmaf(z1, sc.y, sh.y), 0.f);
        o.z = fmaxf(fmaf(z2, sc.z, sh.z), 0.f);
        o.w = fmaxf(fmaf(z3, sc.w, sh.w), 0.f);
        *(float4*)&out[base + (size_t)r * 128 + 4 * s] = o;
    }
}

// ---------------------------------------------------------------------------
extern "C" void kernel_launch(void* const* d_in, const int* in_sizes, int n_in,
                              void* d_out, int out_size, void* d_ws, size_t ws_size,
                              hipStream_t stream)
{
    (void)in_sizes; (void)n_in; (void)out_size; (void)ws_size;

    const float* x   = (const float*)d_in[0];
    const float* W1  = (const float*)d_in[9];
    const float* b1  = (const float*)d_in[10];
    const float* g1  = (const float*)d_in[11];
    const float* be1 = (const float*)d_in[12];
    const float* W2  = (const float*)d_in[13];
    const float* b2  = (const float*)d_in[14];
    const float* g2  = (const float*)d_in[15];
    const float* be2 = (const float*)d_in[16];
    const float* W3  = (const float*)d_in[17];
    const float* b3  = (const float*)d_in[18];
    const float* g3  = (const float*)d_in[19];
    const float* be3 = (const float*)d_in[20];

    char* ws = (char*)d_ws;
    float*   simp   = (float*)(ws + OFF_SIMP);
    ull_*    masks  = (ull_*)(ws + OFF_MASKS);
    ushort_* Wt1    = (ushort_*)(ws + OFF_WT1);
    ushort_* Wt2    = (ushort_*)(ws + OFF_WT2);
    ushort_* Wt3    = (ushort_*)(ws + OFF_WT3);
    float*   bnpart = (float*)(ws + OFF_BNPART);
    double*  bnp2   = (double*)(ws + OFF_BNP2);
    ushort_* Y1t    = (ushort_*)(ws + OFF_Y1T);
    ushort_* Z1     = (ushort_*)(ws + OFF_Z1);
    ushort_* Z2     = (ushort_*)(ws + OFF_Z2);   // reuses simp region
    ushort_* Z3     = (ushort_*)(ws + OFF_Z3);
    float*   out    = (float*)d_out;

    k_prepw<<<dim3(12), dim3(256), 0, stream>>>(W1, W2, W3, Wt1, Wt2, Wt3);
    k_gramg1<<<dim3(512), dim3(512), 0, stream>>>(x, simp, Wt1, Y1t);
    k_simrank<<<dim3(64), dim3(1024), 0, stream>>>(simp, masks);

    k_mix1<<<dim3(512), dim3(256), 0, stream>>>(Y1t, b1, masks, Z1, bnpart);
    k_bnA<<<dim3(32), dim3(256), 0, stream>>>(bnpart, bnp2);

    k_mgemm23<<<dim3(512), dim3(256), 0, stream>>>(Z1, bnp2, g1, be1, Wt2, b2, masks, Z2, bnpart);
    k_bnA<<<dim3(32), dim3(256), 0, stream>>>(bnpart, bnp2);

    k_mgemm23<<<dim3(512), dim3(256), 0, stream>>>(Z2, bnp2, g2, be2, Wt3, b3, masks, Z3, bnpart);
    k_bnA<<<dim3(32), dim3(256), 0, stream>>>(bnpart, bnp2);

    k_out<<<dim3(512), dim3(256), 0, stream>>>(Z3, bnp2, g3, be3, out);
}